// Round 8
// baseline (358.672 us; speedup 1.0000x reference)
//
#include <hip/hip_runtime.h>
#include <math.h>

#define BB   8192
#define NIN  1433
#define NH   64
#define SUBG 6
#define HID  128

typedef __attribute__((ext_vector_type(8))) short bf16x8;
typedef __attribute__((ext_vector_type(4))) float f32x4;
typedef __attribute__((ext_vector_type(16))) float f32x16;

__device__ __forceinline__ short f2bf(float x) {
  unsigned u = __float_as_uint(x);
  unsigned r = (u + 0x7fffu + ((u >> 16) & 1u)) >> 16;   // RNE
  return (short)r;
}
__device__ __forceinline__ float bf2f(short s) {
  return __uint_as_float(((unsigned)(unsigned short)s) << 16);
}
__device__ __forceinline__ float allred64(float v) {
#pragma unroll
  for (int m = 1; m < 64; m <<= 1) v += __shfl_xor(v, m, 64);
  return v;
}

#define WAITV(N)                                            \
  {                                                         \
    asm volatile("s_waitcnt vmcnt(" #N ")" ::: "memory");   \
    __builtin_amdgcn_sched_barrier(0);                      \
  }

// ---------------- prep A: 16x16-fragment pack (decoder weights) ----------------
__global__ void pack_kernel(const float* __restrict__ src, short* __restrict__ hi,
                            short* __restrict__ lo, int Oreal, int NF, int Kreal, int nchunk) {
  int idx = blockIdx.x * 256 + threadIdx.x;
  int total = nchunk * NF * 512;
  if (idx >= total) return;
  int j    = idx & 7;
  int lane = (idx >> 3) & 63;
  int nf   = (idx >> 9) % NF;
  int c    = idx / (NF * 512);
  int o = nf * 16 + (lane & 15);
  int k = c * 32 + ((lane >> 4) << 3) + j;
  float v = (o < Oreal && k < Kreal) ? src[(size_t)o * Kreal + k] : 0.f;
  short h = f2bf(v);
  hi[idx] = h;
  lo[idx] = f2bf(v - bf2f(h));
}

// ---------------- prep B: 32x32-fragment pack (GCN weights) ----------------
// dst[((c*4 + s)*64 + lane)*8 + j], s = kstep*2 + ct:
//   o = (s&1)*32 + (lane&31), k = c*32 + (s>>1)*16 + (lane>>5)*8 + j
__global__ void pack32_kernel(const float* __restrict__ src, short* __restrict__ hi,
                              short* __restrict__ lo) {
  int idx = blockIdx.x * 256 + threadIdx.x;
  if (idx >= 45 * 4 * 512) return;
  int j    = idx & 7;
  int lane = (idx >> 3) & 63;
  int s    = (idx >> 9) & 3;
  int c    = idx >> 11;
  int o = (s & 1) * 32 + (lane & 31);
  int k = c * 32 + ((s >> 1) << 4) + ((lane >> 5) << 3) + j;
  float v = (k < NIN) ? src[(size_t)o * NIN + k] : 0.f;
  short h = f2bf(v);
  hi[idx] = h;
  lo[idx] = f2bf(v - bf2f(h));
}

// ---------------- Kernel 1: GCN matmul, 32x32 MFMA, barrier-free, B in registers ----------------
// 256 threads (4 waves), wave: 32 rows x 64 cols -> block 128 rows. grid 768 ([0,384)=seq1).
// Per chunk per wave: 4 asm A-dwordx4 + 8 asm B-dwordx4 (L1/L2-hit), depth-2, vmcnt(12).
// Zero LDS, zero barriers: waves free-run.
__global__ __launch_bounds__(256, 3) void gcn_mfma(
    const float* __restrict__ seq1, const float* __restrict__ seq2,
    const short* __restrict__ Gh, const short* __restrict__ Gl,
    float* __restrict__ fts1, float* __restrict__ fts2)
{
  const int tid = threadIdx.x;
  const int sid = (blockIdx.x >= 384);
  const int bb  = sid ? (blockIdx.x - 384) : blockIdx.x;
  const float* __restrict__ seq = sid ? seq2 : seq1;
  float* __restrict__ fout = sid ? fts2 : fts1;
  const int w = tid >> 6, lane = tid & 63;
  const int l31 = lane & 31, lg2 = lane >> 5;
  const int row0 = bb * 128 + w * 32;            // wave's first row

  f32x16 acc[2];
#pragma unroll
  for (int i = 0; i < 16; ++i) { acc[0][i] = 0.f; acc[1][i] = 0.f; }

  const float* aptr = seq + (size_t)(row0 + l31) * NIN + lg2 * 8;

  // A chunk c: 16 floats per lane = 4 dwordx4 at byte offsets 0,16,64,80
#define ALOAD(c_, R_)                                                        \
  {                                                                          \
    const float* ad_ = aptr + (c_) * 32;                                     \
    asm volatile(                                                            \
        "global_load_dwordx4 %0, %4, off\n\t"                                \
        "global_load_dwordx4 %1, %4, off offset:16\n\t"                      \
        "global_load_dwordx4 %2, %4, off offset:64\n\t"                      \
        "global_load_dwordx4 %3, %4, off offset:80"                          \
        : "=&v"(R_[0]), "=&v"(R_[1]), "=&v"(R_[2]), "=&v"(R_[3])             \
        : "v"(ad_));                                                         \
  }

  // B chunk c: pieces s=0..3 hi + lo; piece s at byte offset s*1024 from base
#define BLOAD(c_, H_, L_)                                                    \
  {                                                                          \
    const short* bh_ = Gh + ((size_t)(c_) * 256 + lane) * 8;                 \
    const short* bl_ = Gl + ((size_t)(c_) * 256 + lane) * 8;                 \
    asm volatile(                                                            \
        "global_load_dwordx4 %0, %4, off\n\t"                                \
        "global_load_dwordx4 %1, %4, off offset:1024\n\t"                    \
        "global_load_dwordx4 %2, %4, off offset:2048\n\t"                    \
        "global_load_dwordx4 %3, %4, off offset:3072"                        \
        : "=&v"(H_[0]), "=&v"(H_[1]), "=&v"(H_[2]), "=&v"(H_[3])             \
        : "v"(bh_));                                                         \
    asm volatile(                                                            \
        "global_load_dwordx4 %0, %4, off\n\t"                                \
        "global_load_dwordx4 %1, %4, off offset:1024\n\t"                    \
        "global_load_dwordx4 %2, %4, off offset:2048\n\t"                    \
        "global_load_dwordx4 %3, %4, off offset:3072"                        \
        : "=&v"(L_[0]), "=&v"(L_[1]), "=&v"(L_[2]), "=&v"(L_[3])             \
        : "v"(bl_));                                                         \
  }

  // split 8 floats into truncated-hi bf16 + RNE-lo bf16 (residual exact -> 2^-17 rel)
  auto SPLIT8 = [&](const f32x4& p, const f32x4& q, bf16x8& H, bf16x8& L) {
    float av[8] = {p[0], p[1], p[2], p[3], q[0], q[1], q[2], q[3]};
#pragma unroll
    for (int j = 0; j < 8; ++j) {
      unsigned u = __float_as_uint(av[j]);
      H[j] = (short)(u >> 16);
      L[j] = f2bf(av[j] - __uint_as_float(u & 0xffff0000u));
    }
  };

  auto COMPUTE = [&](const f32x4* R, const bf16x8* H, const bf16x8* L) {
    bf16x8 Ah0, Al0, Ah1, Al1;
    SPLIT8(R[0], R[1], Ah0, Al0);     // kstep 0
    SPLIT8(R[2], R[3], Ah1, Al1);     // kstep 1
    __builtin_amdgcn_s_setprio(1);
#pragma unroll
    for (int ct = 0; ct < 2; ++ct) {
      acc[ct] = __builtin_amdgcn_mfma_f32_32x32x16_bf16(Ah0, H[ct],     acc[ct], 0, 0, 0);
      acc[ct] = __builtin_amdgcn_mfma_f32_32x32x16_bf16(Al0, H[ct],     acc[ct], 0, 0, 0);
      acc[ct] = __builtin_amdgcn_mfma_f32_32x32x16_bf16(Ah0, L[ct],     acc[ct], 0, 0, 0);
      acc[ct] = __builtin_amdgcn_mfma_f32_32x32x16_bf16(Ah1, H[2 + ct], acc[ct], 0, 0, 0);
      acc[ct] = __builtin_amdgcn_mfma_f32_32x32x16_bf16(Al1, H[2 + ct], acc[ct], 0, 0, 0);
      acc[ct] = __builtin_amdgcn_mfma_f32_32x32x16_bf16(Ah1, L[2 + ct], acc[ct], 0, 0, 0);
    }
    __builtin_amdgcn_s_setprio(0);
  };

  f32x4 A0[4], A1[4];
  bf16x8 H0[4], L0[4], H1[4], L1[4];

  // prologue: groups 0,1 (each = 12 vmem instrs/thread)
  ALOAD(0, A0); BLOAD(0, H0, L0);
  ALOAD(1, A1); BLOAD(1, H1, L1);

  // bodies 0..41: WAITV(12) drains group c; compute; issue group c+2
#pragma unroll 1
  for (int cc = 0; cc < 42; cc += 2) {
    WAITV(12);
    COMPUTE(A0, H0, L0);
    ALOAD(cc + 2, A0); BLOAD(cc + 2, H0, L0);
    WAITV(12);
    COMPUTE(A1, H1, L1);
    ALOAD(cc + 3, A1); BLOAD(cc + 3, H1, L1);
  }
  // bodies 42,43
  WAITV(12);
  COMPUTE(A0, H0, L0);
  WAITV(0);
  COMPUTE(A1, H1, L1);

  // epilogue chunk 44: k = 1408..1439 (guard A; B zero-padded, plain loads)
  {
    const int k0 = 44 * 32 + lg2 * 8;
    float av[16];
#pragma unroll
    for (int j = 0; j < 8; ++j) {
      int ka = k0 + j, kb = k0 + 16 + j;
      av[j]     = (ka < NIN) ? aptr[44 * 32 + j] : 0.f;
      av[8 + j] = (kb < NIN) ? aptr[44 * 32 + 16 + j] : 0.f;
    }
    bf16x8 Ah0, Al0, Ah1, Al1;
#pragma unroll
    for (int j = 0; j < 8; ++j) {
      unsigned u = __float_as_uint(av[j]);
      Ah0[j] = (short)(u >> 16);
      Al0[j] = f2bf(av[j] - __uint_as_float(u & 0xffff0000u));
      u = __float_as_uint(av[8 + j]);
      Ah1[j] = (short)(u >> 16);
      Al1[j] = f2bf(av[8 + j] - __uint_as_float(u & 0xffff0000u));
    }
#pragma unroll
    for (int ct = 0; ct < 2; ++ct) {
      const size_t o0 = ((size_t)(44 * 4 + ct) * 64 + lane) * 8;
      const size_t o1 = ((size_t)(44 * 4 + 2 + ct) * 64 + lane) * 8;
      bf16x8 Bh0 = *(const bf16x8*)(Gh + o0);
      bf16x8 Bl0 = *(const bf16x8*)(Gl + o0);
      bf16x8 Bh1 = *(const bf16x8*)(Gh + o1);
      bf16x8 Bl1 = *(const bf16x8*)(Gl + o1);
      acc[ct] = __builtin_amdgcn_mfma_f32_32x32x16_bf16(Ah0, Bh0, acc[ct], 0, 0, 0);
      acc[ct] = __builtin_amdgcn_mfma_f32_32x32x16_bf16(Al0, Bh0, acc[ct], 0, 0, 0);
      acc[ct] = __builtin_amdgcn_mfma_f32_32x32x16_bf16(Ah0, Bl0, acc[ct], 0, 0, 0);
      acc[ct] = __builtin_amdgcn_mfma_f32_32x32x16_bf16(Ah1, Bh1, acc[ct], 0, 0, 0);
      acc[ct] = __builtin_amdgcn_mfma_f32_32x32x16_bf16(Al1, Bh1, acc[ct], 0, 0, 0);
      acc[ct] = __builtin_amdgcn_mfma_f32_32x32x16_bf16(Ah1, Bl1, acc[ct], 0, 0, 0);
    }
  }

  // store fts: C/D layout row=(reg&3)+8*(reg>>2)+4*lg2, col=ct*32+l31
#pragma unroll
  for (int ct = 0; ct < 2; ++ct)
#pragma unroll
    for (int reg = 0; reg < 16; ++reg) {
      int crow = (reg & 3) + 8 * (reg >> 2) + 4 * lg2;
      fout[(size_t)(row0 + crow) * 64 + ct * 32 + l31] = acc[ct][reg];
    }
#undef ALOAD
#undef BLOAD
}

// ---------------- Kernel 2: adj-combine + sinkhorn + t = discW @ c + h1 write ----------------
__global__ __launch_bounds__(256) void sink_kernel(
    const float* __restrict__ fts1, const float* __restrict__ fts2,
    const float* __restrict__ adj1, const float* __restrict__ adj2,
    const float* __restrict__ resc, const float* __restrict__ discW,
    const float* __restrict__ bias, const float* __restrict__ aP,
    float* __restrict__ out, float* __restrict__ tws, float* __restrict__ h1w)
{
  const int b = (blockIdx.x << 2) + (threadIdx.x >> 6);
  const int lane = threadIdx.x & 63;
  const float* F1 = fts1 + (size_t)b * 384;
  const float* F2 = fts2 + (size_t)b * 384;
  float f1[6], f2[6];
#pragma unroll
  for (int m = 0; m < 6; ++m) { f1[m] = F1[m * 64 + lane]; f2[m] = F2[m * 64 + lane]; }
  const float bv = bias[lane];
  const float a = aP[0];
  const float* A1 = adj1 + (size_t)b * 36;
  const float* A2 = adj2 + (size_t)b * 36;
  float h1v[6], h2v[6];
#pragma unroll
  for (int n = 0; n < 6; ++n) {
    float o1 = bv, o2 = bv;
#pragma unroll
    for (int m = 0; m < 6; ++m) {
      o1 = fmaf(A1[n * 6 + m], f1[m], o1);
      o2 = fmaf(A2[n * 6 + m], f2[m], o2);
    }
    h1v[n] = (o1 >= 0.f) ? o1 : a * o1;
    h2v[n] = (o2 >= 0.f) ? o2 : a * o2;
  }
#pragma unroll
  for (int n = 0; n < 6; ++n) h1w[(size_t)b * 384 + n * 64 + lane] = h1v[n];

  float g1[5], g2[5];
#pragma unroll
  for (int i = 0; i < 4; ++i) { g1[i] = h1v[i]; g2[i] = h2v[i]; }
  g1[4] = h1v[5]; g2[4] = h2v[5];          // swapped row
  const float n1 = h1v[4], n2 = h2v[4];

  {
    float cm = (g1[0] + g1[1] + g1[2] + g1[3] + n1) * 0.2f;
    float t = 0.f;
    const float4* W4 = (const float4*)discW;
#pragma unroll 4
    for (int jq = 0; jq < 16; ++jq) {
      float4 wv = W4[lane * 16 + jq];
      t = fmaf(wv.x, __shfl(cm, 4 * jq, 64), t);
      t = fmaf(wv.y, __shfl(cm, 4 * jq + 1, 64), t);
      t = fmaf(wv.z, __shfl(cm, 4 * jq + 2, 64), t);
      t = fmaf(wv.w, __shfl(cm, 4 * jq + 3, 64), t);
    }
    tws[(size_t)b * 64 + lane] = t;
  }

  float in1[5], in2[5];
#pragma unroll
  for (int i = 0; i < 5; ++i) {
    float s = allred64(g1[i] * g1[i]);
    in1[i] = 1.f / fmaxf(sqrtf(s), 1e-12f);
    s = allred64(g2[i] * g2[i]);
    in2[i] = 1.f / fmaxf(sqrtf(s), 1e-12f);
  }
  float cost[25], P[25];
#pragma unroll
  for (int i = 0; i < 5; ++i)
#pragma unroll
    for (int j = 0; j < 5; ++j) {
      float d = allred64(g1[i] * g2[j]);
      float cv = (1.f - d * in1[i] * in2[j]) * resc[(size_t)b * 25 + i * 5 + j];
      cost[i * 5 + j] = cv;
      P[i * 5 + j] = expf(-20.f * cv);
    }
  float r[5], c[5];
  float rs = 0.f, cs = 0.f;
#pragma unroll
  for (int i = 0; i < 5; ++i) {
    float d = allred64(g1[i] * n2); d = (d <= 0.f) ? 1e-8f : d; r[i] = d; rs += d;
    d = allred64(g2[i] * n1);       d = (d <= 0.f) ? 1e-8f : d; c[i] = d; cs += d;
  }
#pragma unroll
  for (int i = 0; i < 5; ++i) { r[i] = r[i] / rs; c[i] = c[i] / cs; }

  float u[5], v[5];
#pragma unroll
  for (int i = 0; i < 5; ++i) u[i] = 0.2f;
#pragma unroll
  for (int it = 0; it < 5; ++it) {
#pragma unroll
    for (int i = 0; i < 5; ++i) {
      float pv = 0.f;
#pragma unroll
      for (int j = 0; j < 5; ++j) pv = fmaf(P[i * 5 + j], u[j], pv);
      v[i] = r[i] / pv;
    }
#pragma unroll
    for (int i = 0; i < 5; ++i) {
      float pu = 0.f;
#pragma unroll
      for (int j = 0; j < 5; ++j) pu = fmaf(P[j * 5 + i], v[j], pu);
      u[i] = c[i] / pu;
    }
  }
  float S = 0.f;
#pragma unroll
  for (int i = 0; i < 5; ++i)
#pragma unroll
    for (int j = 0; j < 5; ++j)
      S += v[i] * P[i * 5 + j] * u[j] * (1.f - cost[i * 5 + j]);
  if (lane == 0) out[(size_t)b * 1436] = expf(S * 2.5f) * 2.f;
}

// ---------------- Kernel 3a: decoder layers 1+2 (MFMA) -> x3 ----------------
__global__ __launch_bounds__(64) void dec12_mfma(
    const float* __restrict__ h1,
    const short* __restrict__ B1h, const short* __restrict__ B1l,
    const float* __restrict__ b1, const float* __restrict__ a1P,
    const short* __restrict__ B2h, const short* __restrict__ B2l,
    const float* __restrict__ b2, const float* __restrict__ a2P,
    float* __restrict__ x3)
{
  __shared__ float xT[16][132];
  const int lane = threadIdx.x;
  const int l15 = lane & 15, lg = lane >> 4;
  const int r0 = blockIdx.x * 16;

  f32x4 acc[8];
#pragma unroll
  for (int i = 0; i < 8; ++i) acc[i] = (f32x4){0.f, 0.f, 0.f, 0.f};

  // ---- layer 1: K=256, O=128 ----
#pragma unroll
  for (int c = 0; c < 8; ++c) {
    const float* ap = h1 + (size_t)(r0 + l15) * 384 + c * 32 + lg * 8;
    float4 p = *(const float4*)ap;
    float4 q = *(const float4*)(ap + 4);
    float av[8] = {p.x, p.y, p.z, p.w, q.x, q.y, q.z, q.w};
    bf16x8 Ah, Al;
#pragma unroll
    for (int j = 0; j < 8; ++j) { short h = f2bf(av[j]); Ah[j] = h; Al[j] = f2bf(av[j] - bf2f(h)); }
#pragma unroll
    for (int nf = 0; nf < 8; ++nf) {
      size_t off = (((size_t)(c * 8 + nf)) << 9) + (size_t)lane * 8;
      bf16x8 Bh = *(const bf16x8*)(B1h + off);
      bf16x8 Bl = *(const bf16x8*)(B1l + off);
      acc[nf] = __builtin_amdgcn_mfma_f32_16x16x32_bf16(Ah, Bh, acc[nf], 0, 0, 0);
      acc[nf] = __builtin_amdgcn_mfma_f32_16x16x32_bf16(Al, Bh, acc[nf], 0, 0, 0);
      acc[nf] = __builtin_amdgcn_mfma_f32_16x16x32_bf16(Ah, Bl, acc[nf], 0, 0, 0);
    }
  }
  {
    const float a1 = a1P[0];
#pragma unroll
    for (int nf = 0; nf < 8; ++nf) {
      int o = nf * 16 + l15;
      float bv = b1[o];
#pragma unroll
      for (int j = 0; j < 4; ++j) {
        float v = acc[nf][j] + bv;
        xT[lg * 4 + j][o] = (v >= 0.f) ? v : a1 * v;
      }
    }
  }
  __syncthreads();

  // ---- layer 2: K=128, O=128 ----
#pragma unroll
  for (int i = 0; i < 8; ++i) acc[i] = (f32x4){0.f, 0.f, 0.f, 0.f};
#pragma unroll
  for (int c = 0; c < 4; ++c) {
    const float* ap = &xT[l15][c * 32 + lg * 8];
    float4 p = *(const float4*)ap;
    float4 q = *(const float4*)(ap + 4);
    float av[8] = {p.x, p.y, p.z, p.w, q.x, q.y, q.z, q.w};
    bf16x8 Ah, Al;
#pragma unroll
    for (int j = 0; j < 8; ++j) { short h = f2bf(av[j]); Ah[j] = h; Al[j] = f2bf(av[j] - bf2f(h)); }
#pragma unroll
    for (int nf = 0; nf < 8; ++nf) {
      size_t off = (((size_t)(c * 8 + nf)) << 9) + (size_t)lane * 8;
      bf16x8 Bh = *(const bf16x8*)(B2h + off);
      bf16x8 Bl = *(const bf16x8*)(B2l + off);
      acc[nf] = __builtin_amdgcn_mfma_f32_16x16x32_bf16(Ah, Bh, acc[nf], 0, 0, 0);
      acc[nf] = __builtin_amdgcn_mfma_f32_16x16x32_bf16(Al, Bh, acc[nf], 0, 0, 0);
      acc[nf] = __builtin_amdgcn_mfma_f32_16x16x32_bf16(Ah, Bl, acc[nf], 0, 0, 0);
    }
  }
  {
    const float a2 = a2P[0];
#pragma unroll
    for (int nf = 0; nf < 8; ++nf) {
      int o = nf * 16 + l15;
      float bv = b2[o];
#pragma unroll
      for (int j = 0; j < 4; ++j) {
        float v = acc[nf][j] + bv;
        v = (v >= 0.f) ? v : a2 * v;
        x3[(size_t)(r0 + lg * 4 + j) * 128 + o] = v;
      }
    }
  }
}

// ---------------- Kernel 3b: decoder layer 3 (MFMA, nf-split) ----------------
__global__ __launch_bounds__(64) void dec3_mfma(
    const float* __restrict__ x3,
    const short* __restrict__ B3h, const short* __restrict__ B3l,
    const float* __restrict__ b3, const float* __restrict__ a3P,
    float* __restrict__ out)
{
  const int lane = threadIdx.x;
  const int l15 = lane & 15, lg = lane >> 4;
  const int rowblk = blockIdx.x & 511;
  const int nfg = blockIdx.x >> 9;     // 0..5, 15 nf each (90 total)
  const int r0 = rowblk * 16;

  bf16x8 A3h[4], A3l[4];
#pragma unroll
  for (int c = 0; c < 4; ++c) {
    const float* ap = x3 + (size_t)(r0 + l15) * 128 + c * 32 + lg * 8;
    float4 p = *(const float4*)ap;
    float4 q = *(const float4*)(ap + 4);
    float av[8] = {p.x, p.y, p.z, p.w, q.x, q.y, q.z, q.w};
#pragma unroll
    for (int j = 0; j < 8; ++j) {
      short h = f2bf(av[j]); A3h[c][j] = h; A3l[c][j] = f2bf(av[j] - bf2f(h));
    }
  }
  const float a3 = a3P[0];
  for (int t = 0; t < 15; ++t) {
    const int nf = nfg * 15 + t;
    f32x4 acc = (f32x4){0.f, 0.f, 0.f, 0.f};
#pragma unroll
    for (int c = 0; c < 4; ++c) {
      size_t off = (((size_t)(c * 90 + nf)) << 9) + (size_t)lane * 8;
      bf16x8 Bh = *(const bf16x8*)(B3h + off);
      bf16x8 Bl = *(const bf16x8*)(B3l + off);
      acc = __builtin_amdgcn_mfma_f32_16x16x32_bf16(A3h[c], Bh, acc, 0, 0, 0);
      acc = __builtin_amdgcn_mfma_f32_16x16x32_bf16(A3l[c], Bh, acc, 0, 0, 0);
      acc = __builtin_amdgcn_mfma_f32_16x16x32_bf16(A3h[c], Bl, acc, 0, 0, 0);
    }
    const int o = nf * 16 + l15;
    if (o < NIN) {
      float bv = b3[o];
#pragma unroll
      for (int j = 0; j < 4; ++j) {
        float v = acc[j] + bv;
        v = (v >= 0.f) ? v : a3 * v;
        out[(size_t)(r0 + lg * 4 + j) * 1436 + 1 + o] = v;
      }
    }
  }
}

// ---------------- Kernel 4: discriminator logits ----------------
__global__ __launch_bounds__(256) void disc_kernel(
    const float* __restrict__ h1, const float* __restrict__ tws,
    const float* __restrict__ dbP, float* __restrict__ out)
{
  const int b = (blockIdx.x << 2) + (threadIdx.x >> 6);
  const int lane = threadIdx.x & 63;
  float hp = h1[((size_t)b * SUBG + 5) * NH + lane];
  float t0 = tws[(size_t)b * 64 + lane];
  int bp = (b == 0) ? (BB - 2) : (b - 1);
  float tp = tws[(size_t)bp * 64 + lane];
  float s1 = allred64(hp * t0);
  float s2 = allred64(hp * tp);
  if (lane == 0) {
    float db = dbP[0];
    out[(size_t)b * 1436 + 1434] = s1 + db;
    out[(size_t)b * 1436 + 1435] = s2 + db;
  }
}

extern "C" void kernel_launch(void* const* d_in, const int* in_sizes, int n_in,
                              void* d_out, int out_size, void* d_ws, size_t ws_size,
                              hipStream_t stream) {
  (void)in_sizes; (void)n_in; (void)out_size; (void)ws_size;
  const float* seq1  = (const float*)d_in[0];
  const float* seq2  = (const float*)d_in[1];
  const float* adj1  = (const float*)d_in[2];
  const float* adj2  = (const float*)d_in[3];
  const float* resc  = (const float*)d_in[4];
  const float* gcnW  = (const float*)d_in[5];
  const float* gcnB  = (const float*)d_in[6];
  const float* gcnA  = (const float*)d_in[7];
  const float* W1    = (const float*)d_in[8];
  const float* b1    = (const float*)d_in[9];
  const float* a1    = (const float*)d_in[10];
  const float* W2    = (const float*)d_in[11];
  const float* b2    = (const float*)d_in[12];
  const float* a2    = (const float*)d_in[13];
  const float* W3    = (const float*)d_in[14];
  const float* b3    = (const float*)d_in[15];
  const float* a3    = (const float*)d_in[16];
  const float* discW = (const float*)d_in[17];
  const float* discB = (const float*)d_in[18];

  float* fts1 = (float*)d_ws;                     // 8192*384
  float* fts2 = fts1 + (size_t)BB * SUBG * NH;    // 8192*384
  float* h1   = fts2 + (size_t)BB * SUBG * NH;    // 8192*384
  float* tws  = h1  + (size_t)BB * SUBG * NH;     // 8192*64
  float* x3   = tws + (size_t)BB * 64;            // 8192*128
  short* Gh   = (short*)(x3 + (size_t)BB * 128);
  short* Gl   = Gh  + 45 * 4 * 512;
  short* B1h  = Gl  + 45 * 4 * 512;
  short* B1l  = B1h + 8 * 8 * 512;
  short* B2h  = B1l + 8 * 8 * 512;
  short* B2l  = B2h + 4 * 8 * 512;
  short* B3h  = B2l + 4 * 8 * 512;
  short* B3l  = B3h + 4 * 90 * 512;
  float* out  = (float*)d_out;

  pack32_kernel<<<(45 * 4 * 512 + 255) / 256, 256, 0, stream>>>(gcnW, Gh, Gl);
  pack_kernel<<<(8 * 8 * 512 + 255) / 256, 256, 0, stream>>>(W1, B1h, B1l, 128, 8, 256, 8);
  pack_kernel<<<(4 * 8 * 512 + 255) / 256, 256, 0, stream>>>(W2, B2h, B2l, 128, 8, 128, 4);
  pack_kernel<<<(4 * 90 * 512 + 255) / 256, 256, 0, stream>>>(W3, B3h, B3l, 1433, 90, 128, 4);

  gcn_mfma<<<768, 256, 0, stream>>>(seq1, seq2, Gh, Gl, fts1, fts2);
  sink_kernel<<<2048, 256, 0, stream>>>(fts1, fts2, adj1, adj2, resc, discW, gcnB, gcnA,
                                        out, tws, h1);
  dec12_mfma<<<512, 64, 0, stream>>>(h1, B1h, B1l, b1, a1, B2h, B2l, b2, a2, x3);
  dec3_mfma<<<3072, 64, 0, stream>>>(x3, B3h, B3l, b3, a3, out);
  disc_kernel<<<2048, 256, 0, stream>>>(h1, tws, discB, out);
}

// Round 9
// 320.035 us; speedup vs baseline: 1.1207x; 1.1207x over previous
//
#include <hip/hip_runtime.h>
#include <math.h>

#define BB   8192
#define NIN  1433
#define NH   64
#define SUBG 6
#define HID  128

typedef __attribute__((ext_vector_type(8))) short bf16x8;
typedef __attribute__((ext_vector_type(4))) float f32x4;
typedef __attribute__((ext_vector_type(16))) float f32x16;

__device__ __forceinline__ short f2bf(float x) {
  unsigned u = __float_as_uint(x);
  unsigned r = (u + 0x7fffu + ((u >> 16) & 1u)) >> 16;   // RNE
  return (short)r;
}
__device__ __forceinline__ float bf2f(short s) {
  return __uint_as_float(((unsigned)(unsigned short)s) << 16);
}
__device__ __forceinline__ float allred64(float v) {
#pragma unroll
  for (int m = 1; m < 64; m <<= 1) v += __shfl_xor(v, m, 64);
  return v;
}

__device__ __forceinline__ void gload_lds16(const short* g, short* l) {
  __builtin_amdgcn_global_load_lds(
      (const __attribute__((address_space(1))) void*)g,
      (__attribute__((address_space(3))) void*)l, 16, 0, 0);
}

#define WAITV(N)                                            \
  {                                                         \
    asm volatile("s_waitcnt vmcnt(" #N ")" ::: "memory");   \
    __builtin_amdgcn_sched_barrier(0);                      \
  }
#define BARRIER()                                           \
  {                                                         \
    __builtin_amdgcn_s_barrier();                           \
    __builtin_amdgcn_sched_barrier(0);                      \
  }

// ---------------- prep: ONE kernel packs all weights ----------------
// 16x16 pack: dst[((c*NF+nf)*64+lane)*8+j] = W[nf*16+(lane&15)][c*32+(lane>>4)*8+j]
__device__ __forceinline__ void pack16_impl(const float* __restrict__ src,
                                            short* __restrict__ hi, short* __restrict__ lo,
                                            int Oreal, int NF, int Kreal, int idx) {
  int j    = idx & 7;
  int lane = (idx >> 3) & 63;
  int nf   = (idx >> 9) % NF;
  int c    = idx / (NF * 512);
  int o = nf * 16 + (lane & 15);
  int k = c * 32 + ((lane >> 4) << 3) + j;
  float v = (o < Oreal && k < Kreal) ? src[(size_t)o * Kreal + k] : 0.f;
  short h = f2bf(v);
  hi[idx] = h;
  lo[idx] = f2bf(v - bf2f(h));
}

// 32x32 pack (GCN): dst[((c*4+s)*64+lane)*8+j], o=(s&1)*32+(lane&31),
// k = c*32 + (s>>1)*16 + (lane>>5)*8 + j
__device__ __forceinline__ void pack32_impl(const float* __restrict__ src,
                                            short* __restrict__ hi, short* __restrict__ lo,
                                            int idx) {
  int j    = idx & 7;
  int lane = (idx >> 3) & 63;
  int s    = (idx >> 9) & 3;
  int c    = idx >> 11;
  int o = (s & 1) * 32 + (lane & 31);
  int k = c * 32 + ((s >> 1) << 4) + ((lane >> 5) << 3) + j;
  float v = (k < NIN) ? src[(size_t)o * NIN + k] : 0.f;
  short h = f2bf(v);
  hi[idx] = h;
  lo[idx] = f2bf(v - bf2f(h));
}

#define PK_G  (45 * 4 * 512)     // 92160
#define PK_B1 (8 * 8 * 512)      // 32768
#define PK_B2 (4 * 8 * 512)      // 16384
#define PK_B3 (4 * 90 * 512)     // 184320
#define PK_TOTAL (PK_G + PK_B1 + PK_B2 + PK_B3)

__global__ void pack_all(const float* __restrict__ gcnW, const float* __restrict__ W1,
                         const float* __restrict__ W2, const float* __restrict__ W3,
                         short* Gh, short* Gl, short* B1h, short* B1l,
                         short* B2h, short* B2l, short* B3h, short* B3l) {
  int idx = blockIdx.x * 256 + threadIdx.x;
  if (idx < PK_G) { pack32_impl(gcnW, Gh, Gl, idx); return; }
  idx -= PK_G;
  if (idx < PK_B1) { pack16_impl(W1, B1h, B1l, 128, 8, 256, idx); return; }
  idx -= PK_B1;
  if (idx < PK_B2) { pack16_impl(W2, B2h, B2l, 128, 8, 128, idx); return; }
  idx -= PK_B2;
  if (idx < PK_B3) { pack16_impl(W3, B3h, B3l, 1433, 90, 128, idx); }
}

// ---------------- Kernel 1: GCN matmul (R7 structure, unchanged) ----------------
// 384 threads (6 waves), wave: 32 rows x 64 cols -> block 192 rows. grid 512.
__global__ __launch_bounds__(384, 3) void gcn_mfma(
    const float* __restrict__ seq1, const float* __restrict__ seq2,
    const short* __restrict__ Gh, const short* __restrict__ Gl,
    float* __restrict__ fts1, float* __restrict__ fts2)
{
  __shared__ short sB[4][4096];
  const int tid = threadIdx.x;
  const int sid = blockIdx.x >> 8;
  const int bb  = blockIdx.x & 255;
  const float* __restrict__ seq = sid ? seq2 : seq1;
  float* __restrict__ fout = sid ? fts2 : fts1;
  const int w = tid >> 6, lane = tid & 63;
  const int l31 = lane & 31, lg2 = lane >> 5;
  const int row0 = bb * 192 + w * 32;

  f32x16 acc[2];
#pragma unroll
  for (int i = 0; i < 16; ++i) { acc[0][i] = 0.f; acc[1][i] = 0.f; }

  const float* aptr = seq + (size_t)(row0 + l31) * NIN + lg2 * 8;

  auto STAGE = [&](int c, int slot) {
    short* sb = &sB[slot][0];
    const size_t cb = (size_t)c * 256;
#pragma unroll
    for (int i = 0; i < 2; ++i) {
      const int pb = (w * 128 + i * 64) & 511;
      const short* src = (pb < 256) ? (Gh + (cb + pb) * 8 + (size_t)lane * 8)
                                    : (Gl + (cb + (pb - 256)) * 8 + (size_t)lane * 8);
      gload_lds16(src, sb + (pb + lane) * 8);
    }
  };

#define ALOAD(c_, R_)                                                        \
  {                                                                          \
    const float* ad_ = aptr + (c_) * 32;                                     \
    asm volatile(                                                            \
        "global_load_dwordx4 %0, %4, off\n\t"                                \
        "global_load_dwordx4 %1, %4, off offset:16\n\t"                      \
        "global_load_dwordx4 %2, %4, off offset:64\n\t"                      \
        "global_load_dwordx4 %3, %4, off offset:80"                          \
        : "=&v"(R_[0]), "=&v"(R_[1]), "=&v"(R_[2]), "=&v"(R_[3])             \
        : "v"(ad_));                                                         \
  }

  auto SPLIT8 = [&](const f32x4& p, const f32x4& q, bf16x8& H, bf16x8& L) {
    float av[8] = {p[0], p[1], p[2], p[3], q[0], q[1], q[2], q[3]};
#pragma unroll
    for (int j = 0; j < 8; ++j) {
      unsigned u = __float_as_uint(av[j]);
      H[j] = (short)(u >> 16);
      L[j] = f2bf(av[j] - __uint_as_float(u & 0xffff0000u));
    }
  };

  auto COMPUTE = [&](int c, const f32x4* R) {
    bf16x8 Ah0, Al0, Ah1, Al1;
    SPLIT8(R[0], R[1], Ah0, Al0);
    SPLIT8(R[2], R[3], Ah1, Al1);
    const short* bs = &sB[c & 3][0];
    __builtin_amdgcn_s_setprio(1);
#pragma unroll
    for (int ct = 0; ct < 2; ++ct) {
      bf16x8 Bh0 = *(const bf16x8*)(bs + ((0 + ct) * 64 + lane) * 8);
      bf16x8 Bl0 = *(const bf16x8*)(bs + 2048 + ((0 + ct) * 64 + lane) * 8);
      bf16x8 Bh1 = *(const bf16x8*)(bs + ((2 + ct) * 64 + lane) * 8);
      bf16x8 Bl1 = *(const bf16x8*)(bs + 2048 + ((2 + ct) * 64 + lane) * 8);
      acc[ct] = __builtin_amdgcn_mfma_f32_32x32x16_bf16(Ah0, Bh0, acc[ct], 0, 0, 0);
      acc[ct] = __builtin_amdgcn_mfma_f32_32x32x16_bf16(Al0, Bh0, acc[ct], 0, 0, 0);
      acc[ct] = __builtin_amdgcn_mfma_f32_32x32x16_bf16(Ah0, Bl0, acc[ct], 0, 0, 0);
      acc[ct] = __builtin_amdgcn_mfma_f32_32x32x16_bf16(Ah1, Bh1, acc[ct], 0, 0, 0);
      acc[ct] = __builtin_amdgcn_mfma_f32_32x32x16_bf16(Al1, Bh1, acc[ct], 0, 0, 0);
      acc[ct] = __builtin_amdgcn_mfma_f32_32x32x16_bf16(Ah1, Bl1, acc[ct], 0, 0, 0);
    }
    __builtin_amdgcn_s_setprio(0);
  };

  f32x4 A0[4], A1[4];
  STAGE(0, 0); ALOAD(0, A0);
  STAGE(1, 1); ALOAD(1, A1);

#pragma unroll 1
  for (int cc = 0; cc < 42; cc += 2) {
    WAITV(6); BARRIER();
    COMPUTE(cc, A0);
    STAGE(cc + 2, (cc + 2) & 3); ALOAD(cc + 2, A0);
    WAITV(6); BARRIER();
    COMPUTE(cc + 1, A1);
    STAGE(cc + 3, (cc + 3) & 3); ALOAD(cc + 3, A1);
  }
  WAITV(6); BARRIER();
  COMPUTE(42, A0);
  WAITV(0); BARRIER();
  COMPUTE(43, A1);

  // epilogue chunk 44
  {
    const int k0 = 44 * 32 + lg2 * 8;
    float av[16];
#pragma unroll
    for (int j = 0; j < 8; ++j) {
      int ka = k0 + j, kb = k0 + 16 + j;
      av[j]     = (ka < NIN) ? aptr[44 * 32 + j] : 0.f;
      av[8 + j] = (kb < NIN) ? aptr[44 * 32 + 16 + j] : 0.f;
    }
    bf16x8 Ah0, Al0, Ah1, Al1;
#pragma unroll
    for (int j = 0; j < 8; ++j) {
      unsigned u = __float_as_uint(av[j]);
      Ah0[j] = (short)(u >> 16);
      Al0[j] = f2bf(av[j] - __uint_as_float(u & 0xffff0000u));
      u = __float_as_uint(av[8 + j]);
      Ah1[j] = (short)(u >> 16);
      Al1[j] = f2bf(av[8 + j] - __uint_as_float(u & 0xffff0000u));
    }
#pragma unroll
    for (int ct = 0; ct < 2; ++ct) {
      const size_t o0 = ((size_t)(44 * 4 + ct) * 64 + lane) * 8;
      const size_t o1 = ((size_t)(44 * 4 + 2 + ct) * 64 + lane) * 8;
      bf16x8 Bh0 = *(const bf16x8*)(Gh + o0);
      bf16x8 Bl0 = *(const bf16x8*)(Gl + o0);
      bf16x8 Bh1 = *(const bf16x8*)(Gh + o1);
      bf16x8 Bl1 = *(const bf16x8*)(Gl + o1);
      acc[ct] = __builtin_amdgcn_mfma_f32_32x32x16_bf16(Ah0, Bh0, acc[ct], 0, 0, 0);
      acc[ct] = __builtin_amdgcn_mfma_f32_32x32x16_bf16(Al0, Bh0, acc[ct], 0, 0, 0);
      acc[ct] = __builtin_amdgcn_mfma_f32_32x32x16_bf16(Ah0, Bl0, acc[ct], 0, 0, 0);
      acc[ct] = __builtin_amdgcn_mfma_f32_32x32x16_bf16(Ah1, Bh1, acc[ct], 0, 0, 0);
      acc[ct] = __builtin_amdgcn_mfma_f32_32x32x16_bf16(Al1, Bh1, acc[ct], 0, 0, 0);
      acc[ct] = __builtin_amdgcn_mfma_f32_32x32x16_bf16(Ah1, Bl1, acc[ct], 0, 0, 0);
    }
  }

#pragma unroll
  for (int ct = 0; ct < 2; ++ct)
#pragma unroll
    for (int reg = 0; reg < 16; ++reg) {
      int crow = (reg & 3) + 8 * (reg >> 2) + 4 * lg2;
      fout[(size_t)(row0 + crow) * 64 + ct * 32 + l31] = acc[ct][reg];
    }
#undef ALOAD
}

// ---------------- Kernel 2: adj-combine + sinkhorn + t = discW @ c + h1 write ----------------
__global__ __launch_bounds__(256) void sink_kernel(
    const float* __restrict__ fts1, const float* __restrict__ fts2,
    const float* __restrict__ adj1, const float* __restrict__ adj2,
    const float* __restrict__ resc, const float* __restrict__ discW,
    const float* __restrict__ bias, const float* __restrict__ aP,
    float* __restrict__ out, float* __restrict__ tws, float* __restrict__ h1w)
{
  const int b = (blockIdx.x << 2) + (threadIdx.x >> 6);
  const int lane = threadIdx.x & 63;
  const float* F1 = fts1 + (size_t)b * 384;
  const float* F2 = fts2 + (size_t)b * 384;
  float f1[6], f2[6];
#pragma unroll
  for (int m = 0; m < 6; ++m) { f1[m] = F1[m * 64 + lane]; f2[m] = F2[m * 64 + lane]; }
  const float bv = bias[lane];
  const float a = aP[0];
  const float* A1 = adj1 + (size_t)b * 36;
  const float* A2 = adj2 + (size_t)b * 36;
  float h1v[6], h2v[6];
#pragma unroll
  for (int n = 0; n < 6; ++n) {
    float o1 = bv, o2 = bv;
#pragma unroll
    for (int m = 0; m < 6; ++m) {
      o1 = fmaf(A1[n * 6 + m], f1[m], o1);
      o2 = fmaf(A2[n * 6 + m], f2[m], o2);
    }
    h1v[n] = (o1 >= 0.f) ? o1 : a * o1;
    h2v[n] = (o2 >= 0.f) ? o2 : a * o2;
  }
#pragma unroll
  for (int n = 0; n < 6; ++n) h1w[(size_t)b * 384 + n * 64 + lane] = h1v[n];

  float g1[5], g2[5];
#pragma unroll
  for (int i = 0; i < 4; ++i) { g1[i] = h1v[i]; g2[i] = h2v[i]; }
  g1[4] = h1v[5]; g2[4] = h2v[5];
  const float n1 = h1v[4], n2 = h2v[4];

  {
    float cm = (g1[0] + g1[1] + g1[2] + g1[3] + n1) * 0.2f;
    float t = 0.f;
    const float4* W4 = (const float4*)discW;
#pragma unroll 4
    for (int jq = 0; jq < 16; ++jq) {
      float4 wv = W4[lane * 16 + jq];
      t = fmaf(wv.x, __shfl(cm, 4 * jq, 64), t);
      t = fmaf(wv.y, __shfl(cm, 4 * jq + 1, 64), t);
      t = fmaf(wv.z, __shfl(cm, 4 * jq + 2, 64), t);
      t = fmaf(wv.w, __shfl(cm, 4 * jq + 3, 64), t);
    }
    tws[(size_t)b * 64 + lane] = t;
  }

  float in1[5], in2[5];
#pragma unroll
  for (int i = 0; i < 5; ++i) {
    float s = allred64(g1[i] * g1[i]);
    in1[i] = 1.f / fmaxf(sqrtf(s), 1e-12f);
    s = allred64(g2[i] * g2[i]);
    in2[i] = 1.f / fmaxf(sqrtf(s), 1e-12f);
  }
  float cost[25], P[25];
#pragma unroll
  for (int i = 0; i < 5; ++i)
#pragma unroll
    for (int j = 0; j < 5; ++j) {
      float d = allred64(g1[i] * g2[j]);
      float cv = (1.f - d * in1[i] * in2[j]) * resc[(size_t)b * 25 + i * 5 + j];
      cost[i * 5 + j] = cv;
      P[i * 5 + j] = expf(-20.f * cv);
    }
  float r[5], c[5];
  float rs = 0.f, cs = 0.f;
#pragma unroll
  for (int i = 0; i < 5; ++i) {
    float d = allred64(g1[i] * n2); d = (d <= 0.f) ? 1e-8f : d; r[i] = d; rs += d;
    d = allred64(g2[i] * n1);       d = (d <= 0.f) ? 1e-8f : d; c[i] = d; cs += d;
  }
#pragma unroll
  for (int i = 0; i < 5; ++i) { r[i] = r[i] / rs; c[i] = c[i] / cs; }

  float u[5], v[5];
#pragma unroll
  for (int i = 0; i < 5; ++i) u[i] = 0.2f;
#pragma unroll
  for (int it = 0; it < 5; ++it) {
#pragma unroll
    for (int i = 0; i < 5; ++i) {
      float pv = 0.f;
#pragma unroll
      for (int j = 0; j < 5; ++j) pv = fmaf(P[i * 5 + j], u[j], pv);
      v[i] = r[i] / pv;
    }
#pragma unroll
    for (int i = 0; i < 5; ++i) {
      float pu = 0.f;
#pragma unroll
      for (int j = 0; j < 5; ++j) pu = fmaf(P[j * 5 + i], v[j], pu);
      u[i] = c[i] / pu;
    }
  }
  float S = 0.f;
#pragma unroll
  for (int i = 0; i < 5; ++i)
#pragma unroll
    for (int j = 0; j < 5; ++j)
      S += v[i] * P[i * 5 + j] * u[j] * (1.f - cost[i * 5 + j]);
  if (lane == 0) out[(size_t)b * 1436] = expf(S * 2.5f) * 2.f;
}

// ---------------- Kernel 3: fused decoder (L1+L2+L3 in LDS) + discriminator ----------------
// 512 blocks x 256 thr (4 waves). Block = 16 batches (rows). x3 never leaves LDS.
__global__ __launch_bounds__(256) void dec_fused(
    const float* __restrict__ h1,
    const short* __restrict__ B1h, const short* __restrict__ B1l,
    const float* __restrict__ b1, const float* __restrict__ a1P,
    const short* __restrict__ B2h, const short* __restrict__ B2l,
    const float* __restrict__ b2, const float* __restrict__ a2P,
    const short* __restrict__ B3h, const short* __restrict__ B3l,
    const float* __restrict__ b3, const float* __restrict__ a3P,
    const float* __restrict__ tws, const float* __restrict__ dbP,
    float* __restrict__ out)
{
  __shared__ float xT[16][132];
  __shared__ float x2T[16][132];
  const int tid = threadIdx.x;
  const int w = tid >> 6, lane = tid & 63;
  const int l15 = lane & 15, lg = lane >> 4;
  const int r0 = blockIdx.x * 16;

  // ---- layer 1: K=256, O=128; wave w handles nf = 2w, 2w+1 ----
  f32x4 acc1[2];
  acc1[0] = (f32x4){0.f, 0.f, 0.f, 0.f};
  acc1[1] = (f32x4){0.f, 0.f, 0.f, 0.f};
#pragma unroll
  for (int c = 0; c < 8; ++c) {
    const float* ap = h1 + (size_t)(r0 + l15) * 384 + c * 32 + lg * 8;
    float4 p = *(const float4*)ap;
    float4 q = *(const float4*)(ap + 4);
    float av[8] = {p.x, p.y, p.z, p.w, q.x, q.y, q.z, q.w};
    bf16x8 Ah, Al;
#pragma unroll
    for (int j = 0; j < 8; ++j) { short h = f2bf(av[j]); Ah[j] = h; Al[j] = f2bf(av[j] - bf2f(h)); }
#pragma unroll
    for (int i = 0; i < 2; ++i) {
      const int nf = 2 * w + i;
      size_t off = (((size_t)(c * 8 + nf)) << 9) + (size_t)lane * 8;
      bf16x8 Bh = *(const bf16x8*)(B1h + off);
      bf16x8 Bl = *(const bf16x8*)(B1l + off);
      acc1[i] = __builtin_amdgcn_mfma_f32_16x16x32_bf16(Ah, Bh, acc1[i], 0, 0, 0);
      acc1[i] = __builtin_amdgcn_mfma_f32_16x16x32_bf16(Al, Bh, acc1[i], 0, 0, 0);
      acc1[i] = __builtin_amdgcn_mfma_f32_16x16x32_bf16(Ah, Bl, acc1[i], 0, 0, 0);
    }
  }
  {
    const float a1 = a1P[0];
#pragma unroll
    for (int i = 0; i < 2; ++i) {
      int o = (2 * w + i) * 16 + l15;
      float bvv = b1[o];
#pragma unroll
      for (int j = 0; j < 4; ++j) {
        float v = acc1[i][j] + bvv;
        xT[lg * 4 + j][o] = (v >= 0.f) ? v : a1 * v;
      }
    }
  }
  __syncthreads();

  // ---- layer 2: K=128, O=128; same nf split ----
  acc1[0] = (f32x4){0.f, 0.f, 0.f, 0.f};
  acc1[1] = (f32x4){0.f, 0.f, 0.f, 0.f};
#pragma unroll
  for (int c = 0; c < 4; ++c) {
    const float* ap = &xT[l15][c * 32 + lg * 8];
    float4 p = *(const float4*)ap;
    float4 q = *(const float4*)(ap + 4);
    float av[8] = {p.x, p.y, p.z, p.w, q.x, q.y, q.z, q.w};
    bf16x8 Ah, Al;
#pragma unroll
    for (int j = 0; j < 8; ++j) { short h = f2bf(av[j]); Ah[j] = h; Al[j] = f2bf(av[j] - bf2f(h)); }
#pragma unroll
    for (int i = 0; i < 2; ++i) {
      const int nf = 2 * w + i;
      size_t off = (((size_t)(c * 8 + nf)) << 9) + (size_t)lane * 8;
      bf16x8 Bh = *(const bf16x8*)(B2h + off);
      bf16x8 Bl = *(const bf16x8*)(B2l + off);
      acc1[i] = __builtin_amdgcn_mfma_f32_16x16x32_bf16(Ah, Bh, acc1[i], 0, 0, 0);
      acc1[i] = __builtin_amdgcn_mfma_f32_16x16x32_bf16(Al, Bh, acc1[i], 0, 0, 0);
      acc1[i] = __builtin_amdgcn_mfma_f32_16x16x32_bf16(Ah, Bl, acc1[i], 0, 0, 0);
    }
  }
  {
    const float a2 = a2P[0];
#pragma unroll
    for (int i = 0; i < 2; ++i) {
      int o = (2 * w + i) * 16 + l15;
      float bvv = b2[o];
#pragma unroll
      for (int j = 0; j < 4; ++j) {
        float v = acc1[i][j] + bvv;
        x2T[lg * 4 + j][o] = (v >= 0.f) ? v : a2 * v;
      }
    }
  }
  __syncthreads();

  // ---- layer 3: K=128, O=1433; wave w handles nf = w, w+4, w+8, ... ----
  bf16x8 A3h[4], A3l[4];
#pragma unroll
  for (int c = 0; c < 4; ++c) {
    const float* ap = &x2T[l15][c * 32 + lg * 8];
    float4 p = *(const float4*)ap;
    float4 q = *(const float4*)(ap + 4);
    float av[8] = {p.x, p.y, p.z, p.w, q.x, q.y, q.z, q.w};
#pragma unroll
    for (int j = 0; j < 8; ++j) {
      short h = f2bf(av[j]); A3h[c][j] = h; A3l[c][j] = f2bf(av[j] - bf2f(h));
    }
  }
  const float a3 = a3P[0];
#pragma unroll 1
  for (int t = 0; t < 23; ++t) {
    const int nf = w + 4 * t;
    if (nf >= 90) break;
    f32x4 acc = (f32x4){0.f, 0.f, 0.f, 0.f};
#pragma unroll
    for (int c = 0; c < 4; ++c) {
      size_t off = (((size_t)(c * 90 + nf)) << 9) + (size_t)lane * 8;
      bf16x8 Bh = *(const bf16x8*)(B3h + off);
      bf16x8 Bl = *(const bf16x8*)(B3l + off);
      acc = __builtin_amdgcn_mfma_f32_16x16x32_bf16(A3h[c], Bh, acc, 0, 0, 0);
      acc = __builtin_amdgcn_mfma_f32_16x16x32_bf16(A3l[c], Bh, acc, 0, 0, 0);
      acc = __builtin_amdgcn_mfma_f32_16x16x32_bf16(A3h[c], Bl, acc, 0, 0, 0);
    }
    const int o = nf * 16 + l15;
    if (o < NIN) {
      float bvv = b3[o];
#pragma unroll
      for (int j = 0; j < 4; ++j) {
        float v = acc[j] + bvv;
        v = (v >= 0.f) ? v : a3 * v;
        out[(size_t)(r0 + lg * 4 + j) * 1436 + 1 + o] = v;
      }
    }
  }

  // ---- discriminator logits for this block's 16 batches (4 per wave) ----
  {
    const float db = dbP[0];
#pragma unroll
    for (int i = 0; i < 4; ++i) {
      const int bb = r0 + 4 * w + i;
      float hp = h1[(size_t)bb * 384 + 5 * 64 + lane];
      float t0 = tws[(size_t)bb * 64 + lane];
      const int bp = (bb == 0) ? (BB - 2) : (bb - 1);
      float tp = tws[(size_t)bp * 64 + lane];
      float s1 = allred64(hp * t0);
      float s2 = allred64(hp * tp);
      if (lane == 0) {
        out[(size_t)bb * 1436 + 1434] = s1 + db;
        out[(size_t)bb * 1436 + 1435] = s2 + db;
      }
    }
  }
}

extern "C" void kernel_launch(void* const* d_in, const int* in_sizes, int n_in,
                              void* d_out, int out_size, void* d_ws, size_t ws_size,
                              hipStream_t stream) {
  (void)in_sizes; (void)n_in; (void)out_size; (void)ws_size;
  const float* seq1  = (const float*)d_in[0];
  const float* seq2  = (const float*)d_in[1];
  const float* adj1  = (const float*)d_in[2];
  const float* adj2  = (const float*)d_in[3];
  const float* resc  = (const float*)d_in[4];
  const float* gcnW  = (const float*)d_in[5];
  const float* gcnB  = (const float*)d_in[6];
  const float* gcnA  = (const float*)d_in[7];
  const float* W1    = (const float*)d_in[8];
  const float* b1    = (const float*)d_in[9];
  const float* a1    = (const float*)d_in[10];
  const float* W2    = (const float*)d_in[11];
  const float* b2    = (const float*)d_in[12];
  const float* a2    = (const float*)d_in[13];
  const float* W3    = (const float*)d_in[14];
  const float* b3    = (const float*)d_in[15];
  const float* a3    = (const float*)d_in[16];
  const float* discW = (const float*)d_in[17];
  const float* discB = (const float*)d_in[18];

  float* fts1 = (float*)d_ws;                     // 8192*384
  float* fts2 = fts1 + (size_t)BB * SUBG * NH;    // 8192*384
  float* h1   = fts2 + (size_t)BB * SUBG * NH;    // 8192*384
  float* tws  = h1  + (size_t)BB * SUBG * NH;     // 8192*64
  short* Gh   = (short*)(tws + (size_t)BB * 64);
  short* Gl   = Gh  + PK_G;
  short* B1h  = Gl  + PK_G;
  short* B1l  = B1h + PK_B1;
  short* B2h  = B1l + PK_B1;
  short* B2l  = B2h + PK_B2;
  short* B3h  = B2l + PK_B2;
  short* B3l  = B3h + PK_B3;
  float* out  = (float*)d_out;

  pack_all<<<(PK_TOTAL + 255) / 256, 256, 0, stream>>>(
      gcnW, W1, W2, W3, Gh, Gl, B1h, B1l, B2h, B2l, B3h, B3l);

  gcn_mfma<<<512, 384, 0, stream>>>(seq1, seq2, Gh, Gl, fts1, fts2);
  sink_kernel<<<2048, 256, 0, stream>>>(fts1, fts2, adj1, adj2, resc, discW, gcnB, gcnA,
                                        out, tws, h1);
  dec_fused<<<512, 256, 0, stream>>>(h1, B1h, B1l, b1, a1, B2h, B2l, b2, a2,
                                     B3h, B3l, b3, a3, tws, discB, out);
}

// Round 10
// 282.551 us; speedup vs baseline: 1.2694x; 1.1327x over previous
//
#include <hip/hip_runtime.h>
#include <math.h>

#define BB   8192
#define NIN  1433
#define NH   64
#define SUBG 6
#define HID  128

typedef __attribute__((ext_vector_type(8))) short bf16x8;
typedef __attribute__((ext_vector_type(4))) float f32x4;
typedef __attribute__((ext_vector_type(16))) float f32x16;

__device__ __forceinline__ short f2bf(float x) {
  unsigned u = __float_as_uint(x);
  unsigned r = (u + 0x7fffu + ((u >> 16) & 1u)) >> 16;   // RNE
  return (short)r;
}
__device__ __forceinline__ float bf2f(short s) {
  return __uint_as_float(((unsigned)(unsigned short)s) << 16);
}
__device__ __forceinline__ float allred64(float v) {
#pragma unroll
  for (int m = 1; m < 64; m <<= 1) v += __shfl_xor(v, m, 64);
  return v;
}

__device__ __forceinline__ void gload_lds16(const void* g, void* l) {
  __builtin_amdgcn_global_load_lds(
      (const __attribute__((address_space(1))) void*)g,
      (__attribute__((address_space(3))) void*)l, 16, 0, 0);
}

#define WAITV(N)                                            \
  {                                                         \
    asm volatile("s_waitcnt vmcnt(" #N ")" ::: "memory");   \
    __builtin_amdgcn_sched_barrier(0);                      \
  }

// ---------------- prep: ONE kernel packs all weights ----------------
__device__ __forceinline__ void pack16_impl(const float* __restrict__ src,
                                            short* __restrict__ hi, short* __restrict__ lo,
                                            int Oreal, int NF, int Kreal, int idx) {
  int j    = idx & 7;
  int lane = (idx >> 3) & 63;
  int nf   = (idx >> 9) % NF;
  int c    = idx / (NF * 512);
  int o = nf * 16 + (lane & 15);
  int k = c * 32 + ((lane >> 4) << 3) + j;
  float v = (o < Oreal && k < Kreal) ? src[(size_t)o * Kreal + k] : 0.f;
  short h = f2bf(v);
  hi[idx] = h;
  lo[idx] = f2bf(v - bf2f(h));
}

__device__ __forceinline__ void pack32_impl(const float* __restrict__ src,
                                            short* __restrict__ hi, short* __restrict__ lo,
                                            int idx) {
  int j    = idx & 7;
  int lane = (idx >> 3) & 63;
  int s    = (idx >> 9) & 3;
  int c    = idx >> 11;
  int o = (s & 1) * 32 + (lane & 31);
  int k = c * 32 + ((s >> 1) << 4) + ((lane >> 5) << 3) + j;
  float v = (k < NIN) ? src[(size_t)o * NIN + k] : 0.f;
  short h = f2bf(v);
  hi[idx] = h;
  lo[idx] = f2bf(v - bf2f(h));
}

#define PK_G  (45 * 4 * 512)
#define PK_B1 (8 * 8 * 512)
#define PK_B2 (4 * 8 * 512)
#define PK_B3 (4 * 90 * 512)
#define PK_TOTAL (PK_G + PK_B1 + PK_B2 + PK_B3)

__global__ void pack_all(const float* __restrict__ gcnW, const float* __restrict__ W1,
                         const float* __restrict__ W2, const float* __restrict__ W3,
                         short* Gh, short* Gl, short* B1h, short* B1l,
                         short* B2h, short* B2l, short* B3h, short* B3l) {
  int idx = blockIdx.x * 256 + threadIdx.x;
  if (idx < PK_G) { pack32_impl(gcnW, Gh, Gl, idx); return; }
  idx -= PK_G;
  if (idx < PK_B1) { pack16_impl(W1, B1h, B1l, 128, 8, 256, idx); return; }
  idx -= PK_B1;
  if (idx < PK_B2) { pack16_impl(W2, B2h, B2l, 128, 8, 128, idx); return; }
  idx -= PK_B2;
  if (idx < PK_B3) { pack16_impl(W3, B3h, B3l, 1433, 90, 128, idx); }
}

// ---------------- Kernel 1: GCN matmul — coalesced-A via swizzled wave-private LDS ----------------
// 256 threads (4 waves), wave: 32 rows x 64 cols -> block 128 rows. grid 768 ([0,384)=seq1).
// A: global_load_lds with PRE-SWIZZLED per-lane source (8 lanes cover one row's 8x16B pieces,
//    piece pp = lp ^ (row&7)) -> 128B-coalesced HBM reads; ds_read_b128 with same XOR.
// B: registers (contiguous 1KB/instr, L1/L2-hit). No barriers; depth-2 counted vmcnt(12).
__global__ __launch_bounds__(256, 3) void gcn_mfma(
    const float* __restrict__ seq1, const float* __restrict__ seq2,
    const short* __restrict__ Gh, const short* __restrict__ Gl,
    float* __restrict__ fts1, float* __restrict__ fts2)
{
  __shared__ char sA[4][2][4096];   // [wave][slot][32 rows x 128B], XOR-swizzled pieces
  const int tid = threadIdx.x;
  const int sid = (blockIdx.x >= 384);
  const int bb  = sid ? (blockIdx.x - 384) : blockIdx.x;
  const float* __restrict__ seq = sid ? seq2 : seq1;
  float* __restrict__ fout = sid ? fts2 : fts1;
  const int w = tid >> 6, lane = tid & 63;
  const int l31 = lane & 31, lg2 = lane >> 5;
  const int row0 = bb * 128 + w * 32;

  f32x16 acc[2];
#pragma unroll
  for (int i = 0; i < 16; ++i) { acc[0][i] = 0.f; acc[1][i] = 0.f; }

  // staging geometry (per thread, 4 insts): idx = i*64+lane; row = idx>>3; pp = idx&7
  // logical piece lp = pp ^ (row&7) -> per-lane global src; LDS dest linear = idx*16
  int st_row[4], st_lp[4];
#pragma unroll
  for (int i = 0; i < 4; ++i) {
    int idx = i * 64 + lane;
    st_row[i] = idx >> 3;
    st_lp[i]  = (idx & 7) ^ (st_row[i] & 7);
  }

  auto STAGE_A = [&](int c) {
    char* dst = &sA[w][c & 1][0];
#pragma unroll
    for (int i = 0; i < 4; ++i) {
      const float* src = seq + (size_t)(row0 + st_row[i]) * NIN + c * 32 + st_lp[i] * 4;
      gload_lds16(src, dst + i * 1024 + lane * 16);
    }
  };

  // B chunk c into regs: pieces s=0..3 hi + lo, contiguous 1KB per instr
#define BLOAD(c_, H_, L_)                                                    \
  {                                                                          \
    const short* bh_ = Gh + ((size_t)(c_) * 256 + lane) * 8;                 \
    const short* bl_ = Gl + ((size_t)(c_) * 256 + lane) * 8;                 \
    asm volatile(                                                            \
        "global_load_dwordx4 %0, %4, off\n\t"                                \
        "global_load_dwordx4 %1, %4, off offset:1024\n\t"                    \
        "global_load_dwordx4 %2, %4, off offset:2048\n\t"                    \
        "global_load_dwordx4 %3, %4, off offset:3072"                        \
        : "=&v"(H_[0]), "=&v"(H_[1]), "=&v"(H_[2]), "=&v"(H_[3])             \
        : "v"(bh_));                                                         \
    asm volatile(                                                            \
        "global_load_dwordx4 %0, %4, off\n\t"                                \
        "global_load_dwordx4 %1, %4, off offset:1024\n\t"                    \
        "global_load_dwordx4 %2, %4, off offset:2048\n\t"                    \
        "global_load_dwordx4 %3, %4, off offset:3072"                        \
        : "=&v"(L_[0]), "=&v"(L_[1]), "=&v"(L_[2]), "=&v"(L_[3])             \
        : "v"(bl_));                                                         \
  }

  auto SPLIT8 = [&](const f32x4& p, const f32x4& q, bf16x8& H, bf16x8& L) {
    float av[8] = {p[0], p[1], p[2], p[3], q[0], q[1], q[2], q[3]};
#pragma unroll
    for (int j = 0; j < 8; ++j) {
      unsigned u = __float_as_uint(av[j]);
      H[j] = (short)(u >> 16);
      L[j] = f2bf(av[j] - __uint_as_float(u & 0xffff0000u));
    }
  };

  // ds_read offsets (loop-invariant): fragment pieces lp in {2lg2,2lg2+1,2lg2+4,2lg2+5}
  const int rb = l31 * 128;
  const int sw = (l31 & 7) * 16;
  const int o0 = rb + (((2 * lg2 + 0) * 16) ^ sw);
  const int o1 = rb + (((2 * lg2 + 1) * 16) ^ sw);
  const int o2 = rb + (((2 * lg2 + 4) * 16) ^ sw);
  const int o3 = rb + (((2 * lg2 + 5) * 16) ^ sw);

  auto COMPUTE = [&](int c, const bf16x8* H, const bf16x8* L) {
    const char* base = &sA[w][c & 1][0];
    f32x4 p0 = *(const f32x4*)(base + o0);
    f32x4 p1 = *(const f32x4*)(base + o1);
    f32x4 p2 = *(const f32x4*)(base + o2);
    f32x4 p3 = *(const f32x4*)(base + o3);
    bf16x8 Ah0, Al0, Ah1, Al1;
    SPLIT8(p0, p1, Ah0, Al0);
    SPLIT8(p2, p3, Ah1, Al1);
    __builtin_amdgcn_s_setprio(1);
#pragma unroll
    for (int ct = 0; ct < 2; ++ct) {
      acc[ct] = __builtin_amdgcn_mfma_f32_32x32x16_bf16(Ah0, H[ct],     acc[ct], 0, 0, 0);
      acc[ct] = __builtin_amdgcn_mfma_f32_32x32x16_bf16(Al0, H[ct],     acc[ct], 0, 0, 0);
      acc[ct] = __builtin_amdgcn_mfma_f32_32x32x16_bf16(Ah0, L[ct],     acc[ct], 0, 0, 0);
      acc[ct] = __builtin_amdgcn_mfma_f32_32x32x16_bf16(Ah1, H[2 + ct], acc[ct], 0, 0, 0);
      acc[ct] = __builtin_amdgcn_mfma_f32_32x32x16_bf16(Al1, H[2 + ct], acc[ct], 0, 0, 0);
      acc[ct] = __builtin_amdgcn_mfma_f32_32x32x16_bf16(Ah1, L[2 + ct], acc[ct], 0, 0, 0);
    }
    __builtin_amdgcn_s_setprio(0);
  };

  bf16x8 H0[4], L0[4], H1[4], L1[4];

  // prologue: groups 0,1 (each = 4 A-lds + 8 B = 12 vmem/thread)
  STAGE_A(0); BLOAD(0, H0, L0);
  STAGE_A(1); BLOAD(1, H1, L1);

#pragma unroll 1
  for (int cc = 0; cc < 42; cc += 2) {
    WAITV(12);
    COMPUTE(cc, H0, L0);
    __builtin_amdgcn_sched_barrier(0);
    STAGE_A(cc + 2); BLOAD(cc + 2, H0, L0);
    WAITV(12);
    COMPUTE(cc + 1, H1, L1);
    __builtin_amdgcn_sched_barrier(0);
    STAGE_A(cc + 3); BLOAD(cc + 3, H1, L1);
  }
  WAITV(12);
  COMPUTE(42, H0, L0);
  WAITV(0);
  COMPUTE(43, H1, L1);

  // epilogue chunk 44: k = 1408..1439 (guard A; B zero-padded, plain loads)
  {
    const float* aptr = seq + (size_t)(row0 + l31) * NIN + lg2 * 8;
    const int k0 = 44 * 32 + lg2 * 8;
    float av[16];
#pragma unroll
    for (int j = 0; j < 8; ++j) {
      int ka = k0 + j, kb = k0 + 16 + j;
      av[j]     = (ka < NIN) ? aptr[44 * 32 + j] : 0.f;
      av[8 + j] = (kb < NIN) ? aptr[44 * 32 + 16 + j] : 0.f;
    }
    bf16x8 Ah0, Al0, Ah1, Al1;
#pragma unroll
    for (int j = 0; j < 8; ++j) {
      unsigned u = __float_as_uint(av[j]);
      Ah0[j] = (short)(u >> 16);
      Al0[j] = f2bf(av[j] - __uint_as_float(u & 0xffff0000u));
      u = __float_as_uint(av[8 + j]);
      Ah1[j] = (short)(u >> 16);
      Al1[j] = f2bf(av[8 + j] - __uint_as_float(u & 0xffff0000u));
    }
#pragma unroll
    for (int ct = 0; ct < 2; ++ct) {
      const size_t q0 = ((size_t)(44 * 4 + ct) * 64 + lane) * 8;
      const size_t q1 = ((size_t)(44 * 4 + 2 + ct) * 64 + lane) * 8;
      bf16x8 Bh0 = *(const bf16x8*)(Gh + q0);
      bf16x8 Bl0 = *(const bf16x8*)(Gl + q0);
      bf16x8 Bh1 = *(const bf16x8*)(Gh + q1);
      bf16x8 Bl1 = *(const bf16x8*)(Gl + q1);
      acc[ct] = __builtin_amdgcn_mfma_f32_32x32x16_bf16(Ah0, Bh0, acc[ct], 0, 0, 0);
      acc[ct] = __builtin_amdgcn_mfma_f32_32x32x16_bf16(Al0, Bh0, acc[ct], 0, 0, 0);
      acc[ct] = __builtin_amdgcn_mfma_f32_32x32x16_bf16(Ah0, Bl0, acc[ct], 0, 0, 0);
      acc[ct] = __builtin_amdgcn_mfma_f32_32x32x16_bf16(Ah1, Bh1, acc[ct], 0, 0, 0);
      acc[ct] = __builtin_amdgcn_mfma_f32_32x32x16_bf16(Al1, Bh1, acc[ct], 0, 0, 0);
      acc[ct] = __builtin_amdgcn_mfma_f32_32x32x16_bf16(Ah1, Bl1, acc[ct], 0, 0, 0);
    }
  }

  // store fts: C/D layout row=(reg&3)+8*(reg>>2)+4*lg2, col=ct*32+l31
#pragma unroll
  for (int ct = 0; ct < 2; ++ct)
#pragma unroll
    for (int reg = 0; reg < 16; ++reg) {
      int crow = (reg & 3) + 8 * (reg >> 2) + 4 * lg2;
      fout[(size_t)(row0 + crow) * 64 + ct * 32 + l31] = acc[ct][reg];
    }
#undef BLOAD
}

// ---------------- Kernel 2: adj-combine + sinkhorn + t = discW @ c + h1 write ----------------
__global__ __launch_bounds__(256) void sink_kernel(
    const float* __restrict__ fts1, const float* __restrict__ fts2,
    const float* __restrict__ adj1, const float* __restrict__ adj2,
    const float* __restrict__ resc, const float* __restrict__ discW,
    const float* __restrict__ bias, const float* __restrict__ aP,
    float* __restrict__ out, float* __restrict__ tws, float* __restrict__ h1w)
{
  const int b = (blockIdx.x << 2) + (threadIdx.x >> 6);
  const int lane = threadIdx.x & 63;
  const float* F1 = fts1 + (size_t)b * 384;
  const float* F2 = fts2 + (size_t)b * 384;
  float f1[6], f2[6];
#pragma unroll
  for (int m = 0; m < 6; ++m) { f1[m] = F1[m * 64 + lane]; f2[m] = F2[m * 64 + lane]; }
  const float bv = bias[lane];
  const float a = aP[0];
  const float* A1 = adj1 + (size_t)b * 36;
  const float* A2 = adj2 + (size_t)b * 36;
  float h1v[6], h2v[6];
#pragma unroll
  for (int n = 0; n < 6; ++n) {
    float o1 = bv, o2 = bv;
#pragma unroll
    for (int m = 0; m < 6; ++m) {
      o1 = fmaf(A1[n * 6 + m], f1[m], o1);
      o2 = fmaf(A2[n * 6 + m], f2[m], o2);
    }
    h1v[n] = (o1 >= 0.f) ? o1 : a * o1;
    h2v[n] = (o2 >= 0.f) ? o2 : a * o2;
  }
#pragma unroll
  for (int n = 0; n < 6; ++n) h1w[(size_t)b * 384 + n * 64 + lane] = h1v[n];

  float g1[5], g2[5];
#pragma unroll
  for (int i = 0; i < 4; ++i) { g1[i] = h1v[i]; g2[i] = h2v[i]; }
  g1[4] = h1v[5]; g2[4] = h2v[5];
  const float n1 = h1v[4], n2 = h2v[4];

  {
    float cm = (g1[0] + g1[1] + g1[2] + g1[3] + n1) * 0.2f;
    float t = 0.f;
    const float4* W4 = (const float4*)discW;
#pragma unroll 4
    for (int jq = 0; jq < 16; ++jq) {
      float4 wv = W4[lane * 16 + jq];
      t = fmaf(wv.x, __shfl(cm, 4 * jq, 64), t);
      t = fmaf(wv.y, __shfl(cm, 4 * jq + 1, 64), t);
      t = fmaf(wv.z, __shfl(cm, 4 * jq + 2, 64), t);
      t = fmaf(wv.w, __shfl(cm, 4 * jq + 3, 64), t);
    }
    tws[(size_t)b * 64 + lane] = t;
  }

  float in1[5], in2[5];
#pragma unroll
  for (int i = 0; i < 5; ++i) {
    float s = allred64(g1[i] * g1[i]);
    in1[i] = 1.f / fmaxf(sqrtf(s), 1e-12f);
    s = allred64(g2[i] * g2[i]);
    in2[i] = 1.f / fmaxf(sqrtf(s), 1e-12f);
  }
  float cost[25], P[25];
#pragma unroll
  for (int i = 0; i < 5; ++i)
#pragma unroll
    for (int j = 0; j < 5; ++j) {
      float d = allred64(g1[i] * g2[j]);
      float cv = (1.f - d * in1[i] * in2[j]) * resc[(size_t)b * 25 + i * 5 + j];
      cost[i * 5 + j] = cv;
      P[i * 5 + j] = expf(-20.f * cv);
    }
  float r[5], c[5];
  float rs = 0.f, cs = 0.f;
#pragma unroll
  for (int i = 0; i < 5; ++i) {
    float d = allred64(g1[i] * n2); d = (d <= 0.f) ? 1e-8f : d; r[i] = d; rs += d;
    d = allred64(g2[i] * n1);       d = (d <= 0.f) ? 1e-8f : d; c[i] = d; cs += d;
  }
#pragma unroll
  for (int i = 0; i < 5; ++i) { r[i] = r[i] / rs; c[i] = c[i] / cs; }

  float u[5], v[5];
#pragma unroll
  for (int i = 0; i < 5; ++i) u[i] = 0.2f;
#pragma unroll
  for (int it = 0; it < 5; ++it) {
#pragma unroll
    for (int i = 0; i < 5; ++i) {
      float pv = 0.f;
#pragma unroll
      for (int j = 0; j < 5; ++j) pv = fmaf(P[i * 5 + j], u[j], pv);
      v[i] = r[i] / pv;
    }
#pragma unroll
    for (int i = 0; i < 5; ++i) {
      float pu = 0.f;
#pragma unroll
      for (int j = 0; j < 5; ++j) pu = fmaf(P[j * 5 + i], v[j], pu);
      u[i] = c[i] / pu;
    }
  }
  float S = 0.f;
#pragma unroll
  for (int i = 0; i < 5; ++i)
#pragma unroll
    for (int j = 0; j < 5; ++j)
      S += v[i] * P[i * 5 + j] * u[j] * (1.f - cost[i * 5 + j]);
  if (lane == 0) out[(size_t)b * 1436] = expf(S * 2.5f) * 2.f;
}

// ---------------- Kernel 3: fused decoder + discriminator, 8 waves ----------------
// 512 blocks x 512 thr. Block = 16 batches. L3 uses B-hi only (A still split).
__global__ __launch_bounds__(512) void dec_fused(
    const float* __restrict__ h1,
    const short* __restrict__ B1h, const short* __restrict__ B1l,
    const float* __restrict__ b1, const float* __restrict__ a1P,
    const short* __restrict__ B2h, const short* __restrict__ B2l,
    const float* __restrict__ b2, const float* __restrict__ a2P,
    const short* __restrict__ B3h,
    const float* __restrict__ b3, const float* __restrict__ a3P,
    const float* __restrict__ tws, const float* __restrict__ dbP,
    float* __restrict__ out)
{
  __shared__ float xT[16][132];
  __shared__ float x2T[16][132];
  const int tid = threadIdx.x;
  const int w = tid >> 6, lane = tid & 63;
  const int l15 = lane & 15, lg = lane >> 4;
  const int r0 = blockIdx.x * 16;

  // ---- layer 1: K=256, O=128; wave w -> nf = w ----
  f32x4 acc1 = (f32x4){0.f, 0.f, 0.f, 0.f};
#pragma unroll
  for (int c = 0; c < 8; ++c) {
    const float* ap = h1 + (size_t)(r0 + l15) * 384 + c * 32 + lg * 8;
    float4 p = *(const float4*)ap;
    float4 q = *(const float4*)(ap + 4);
    float av[8] = {p.x, p.y, p.z, p.w, q.x, q.y, q.z, q.w};
    bf16x8 Ah, Al;
#pragma unroll
    for (int j = 0; j < 8; ++j) { short h = f2bf(av[j]); Ah[j] = h; Al[j] = f2bf(av[j] - bf2f(h)); }
    size_t off = (((size_t)(c * 8 + w)) << 9) + (size_t)lane * 8;
    bf16x8 Bh = *(const bf16x8*)(B1h + off);
    bf16x8 Bl = *(const bf16x8*)(B1l + off);
    acc1 = __builtin_amdgcn_mfma_f32_16x16x32_bf16(Ah, Bh, acc1, 0, 0, 0);
    acc1 = __builtin_amdgcn_mfma_f32_16x16x32_bf16(Al, Bh, acc1, 0, 0, 0);
    acc1 = __builtin_amdgcn_mfma_f32_16x16x32_bf16(Ah, Bl, acc1, 0, 0, 0);
  }
  {
    const float a1 = a1P[0];
    int o = w * 16 + l15;
    float bvv = b1[o];
#pragma unroll
    for (int j = 0; j < 4; ++j) {
      float v = acc1[j] + bvv;
      xT[lg * 4 + j][o] = (v >= 0.f) ? v : a1 * v;
    }
  }
  __syncthreads();

  // ---- layer 2: K=128, O=128; wave w -> nf = w ----
  acc1 = (f32x4){0.f, 0.f, 0.f, 0.f};
#pragma unroll
  for (int c = 0; c < 4; ++c) {
    const float* ap = &xT[l15][c * 32 + lg * 8];
    float4 p = *(const float4*)ap;
    float4 q = *(const float4*)(ap + 4);
    float av[8] = {p.x, p.y, p.z, p.w, q.x, q.y, q.z, q.w};
    bf16x8 Ah, Al;
#pragma unroll
    for (int j = 0; j < 8; ++j) { short h = f2bf(av[j]); Ah[j] = h; Al[j] = f2bf(av[j] - bf2f(h)); }
    size_t off = (((size_t)(c * 8 + w)) << 9) + (size_t)lane * 8;
    bf16x8 Bh = *(const bf16x8*)(B2h + off);
    bf16x8 Bl = *(const bf16x8*)(B2l + off);
    acc1 = __builtin_amdgcn_mfma_f32_16x16x32_bf16(Ah, Bh, acc1, 0, 0, 0);
    acc1 = __builtin_amdgcn_mfma_f32_16x16x32_bf16(Al, Bh, acc1, 0, 0, 0);
    acc1 = __builtin_amdgcn_mfma_f32_16x16x32_bf16(Ah, Bl, acc1, 0, 0, 0);
  }
  {
    const float a2 = a2P[0];
    int o = w * 16 + l15;
    float bvv = b2[o];
#pragma unroll
    for (int j = 0; j < 4; ++j) {
      float v = acc1[j] + bvv;
      x2T[lg * 4 + j][o] = (v >= 0.f) ? v : a2 * v;
    }
  }
  __syncthreads();

  // ---- layer 3: K=128, O=1433; wave w -> nf = w + 8t; B hi-only ----
  bf16x8 A3h[4], A3l[4];
#pragma unroll
  for (int c = 0; c < 4; ++c) {
    const float* ap = &x2T[l15][c * 32 + lg * 8];
    float4 p = *(const float4*)ap;
    float4 q = *(const float4*)(ap + 4);
    float av[8] = {p.x, p.y, p.z, p.w, q.x, q.y, q.z, q.w};
#pragma unroll
    for (int j = 0; j < 8; ++j) {
      short h = f2bf(av[j]); A3h[c][j] = h; A3l[c][j] = f2bf(av[j] - bf2f(h));
    }
  }
  const float a3 = a3P[0];
#pragma unroll 1
  for (int t = 0; t < 12; ++t) {
    const int nf = w + 8 * t;
    if (nf >= 90) break;
    f32x4 acc = (f32x4){0.f, 0.f, 0.f, 0.f};
#pragma unroll
    for (int c = 0; c < 4; ++c) {
      size_t off = (((size_t)(c * 90 + nf)) << 9) + (size_t)lane * 8;
      bf16x8 Bh = *(const bf16x8*)(B3h + off);
      acc = __builtin_amdgcn_mfma_f32_16x16x32_bf16(A3h[c], Bh, acc, 0, 0, 0);
      acc = __builtin_amdgcn_mfma_f32_16x16x32_bf16(A3l[c], Bh, acc, 0, 0, 0);
    }
    const int o = nf * 16 + l15;
    if (o < NIN) {
      float bvv = b3[o];
#pragma unroll
      for (int j = 0; j < 4; ++j) {
        float v = acc[j] + bvv;
        v = (v >= 0.f) ? v : a3 * v;
        out[(size_t)(r0 + lg * 4 + j) * 1436 + 1 + o] = v;
      }
    }
  }

  // ---- discriminator logits (2 batches per wave) ----
  {
    const float db = dbP[0];
#pragma unroll
    for (int i = 0; i < 2; ++i) {
      const int bb = r0 + 2 * w + i;
      float hp = h1[(size_t)bb * 384 + 5 * 64 + lane];
      float t0 = tws[(size_t)bb * 64 + lane];
      const int bp = (bb == 0) ? (BB - 2) : (bb - 1);
      float tp = tws[(size_t)bp * 64 + lane];
      float s1 = allred64(hp * t0);
      float s2 = allred64(hp * tp);
      if (lane == 0) {
        out[(size_t)bb * 1436 + 1434] = s1 + db;
        out[(size_t)bb * 1436 + 1435] = s2 + db;
      }
    }
  }
}

extern "C" void kernel_launch(void* const* d_in, const int* in_sizes, int n_in,
                              void* d_out, int out_size, void* d_ws, size_t ws_size,
                              hipStream_t stream) {
  (void)in_sizes; (void)n_in; (void)out_size; (void)ws_size;
  const float* seq1  = (const float*)d_in[0];
  const float* seq2  = (const float*)d_in[1];
  const float* adj1  = (const float*)d_in[2];
  const float* adj2  = (const float*)d_in[3];
  const float* resc  = (const float*)d_in[4];
  const float* gcnW  = (const float*)d_in[5];
  const float* gcnB  = (const float*)d_in[6];
  const float* gcnA  = (const float*)d_in[7];
  const float* W1    = (const float*)d_in[8];
  const float* b1    = (const float*)d_in[9];
  const float* a1    = (const float*)d_in[10];
  const float* W2    = (const float*)d_in[11];
  const float* b2    = (const float*)d_in[12];
  const float* a2    = (const float*)d_in[13];
  const float* W3    = (const float*)d_in[14];
  const float* b3    = (const float*)d_in[15];
  const float* a3    = (const float*)d_in[16];
  const float* discW = (const float*)d_in[17];
  const float* discB = (const float*)d_in[18];

  float* fts1 = (float*)d_ws;
  float* fts2 = fts1 + (size_t)BB * SUBG * NH;
  float* h1   = fts2 + (size_t)BB * SUBG * NH;
  float* tws  = h1  + (size_t)BB * SUBG * NH;
  short* Gh   = (short*)(tws + (size_t)BB * 64);
  short* Gl   = Gh  + PK_G;
  short* B1h  = Gl  + PK_G;
  short* B1l  = B1h + PK_B1;
  short* B2h  = B1l + PK_B1;
  short* B2l  = B2h + PK_B2;
  short* B3h  = B2l + PK_B2;
  short* B3l  = B3h + PK_B3;
  float* out  = (float*)d_out;

  pack_all<<<(PK_TOTAL + 255) / 256, 256, 0, stream>>>(
      gcnW, W1, W2, W3, Gh, Gl, B1h, B1l, B2h, B2l, B3h, B3l);

  gcn_mfma<<<768, 256, 0, stream>>>(seq1, seq2, Gh, Gl, fts1, fts2);
  sink_kernel<<<2048, 256, 0, stream>>>(fts1, fts2, adj1, adj2, resc, discW, gcnB, gcnA,
                                        out, tws, h1);
  dec_fused<<<512, 512, 0, stream>>>(h1, B1h, B1l, b1, a1, B2h, B2l, b2, a2,
                                     B3h, b3, a3, tws, discB, out);
}

// Round 11
// 261.898 us; speedup vs baseline: 1.3695x; 1.0789x over previous
//
#include <hip/hip_runtime.h>
#include <math.h>

#define BB   8192
#define NIN  1433
#define NH   64
#define SUBG 6
#define HID  128

typedef __attribute__((ext_vector_type(8))) short bf16x8;
typedef __attribute__((ext_vector_type(4))) float f32x4;
typedef __attribute__((ext_vector_type(16))) float f32x16;

__device__ __forceinline__ short f2bf(float x) {
  unsigned u = __float_as_uint(x);
  unsigned r = (u + 0x7fffu + ((u >> 16) & 1u)) >> 16;   // RNE
  return (short)r;
}
__device__ __forceinline__ float bf2f(short s) {
  return __uint_as_float(((unsigned)(unsigned short)s) << 16);
}
__device__ __forceinline__ float allred64(float v) {
#pragma unroll
  for (int m = 1; m < 64; m <<= 1) v += __shfl_xor(v, m, 64);
  return v;
}

__device__ __forceinline__ void gload_lds16(const void* g, void* l) {
  __builtin_amdgcn_global_load_lds(
      (const __attribute__((address_space(1))) void*)g,
      (__attribute__((address_space(3))) void*)l, 16, 0, 0);
}

#define WAITV(N)                                            \
  {                                                         \
    asm volatile("s_waitcnt vmcnt(" #N ")" ::: "memory");   \
    __builtin_amdgcn_sched_barrier(0);                      \
  }
#define BARRIER()                                           \
  {                                                         \
    __builtin_amdgcn_s_barrier();                           \
    __builtin_amdgcn_sched_barrier(0);                      \
  }

// ---------------- prep: ONE kernel packs all weights ----------------
__device__ __forceinline__ void pack16_impl(const float* __restrict__ src,
                                            short* __restrict__ hi, short* __restrict__ lo,
                                            int Oreal, int NF, int Kreal, int idx) {
  int j    = idx & 7;
  int lane = (idx >> 3) & 63;
  int nf   = (idx >> 9) % NF;
  int c    = idx / (NF * 512);
  int o = nf * 16 + (lane & 15);
  int k = c * 32 + ((lane >> 4) << 3) + j;
  float v = (o < Oreal && k < Kreal) ? src[(size_t)o * Kreal + k] : 0.f;
  short h = f2bf(v);
  hi[idx] = h;
  lo[idx] = f2bf(v - bf2f(h));
}

__device__ __forceinline__ void pack32_impl(const float* __restrict__ src,
                                            short* __restrict__ hi, short* __restrict__ lo,
                                            int idx) {
  int j    = idx & 7;
  int lane = (idx >> 3) & 63;
  int s    = (idx >> 9) & 3;
  int c    = idx >> 11;
  int o = (s & 1) * 32 + (lane & 31);
  int k = c * 32 + ((s >> 1) << 4) + ((lane >> 5) << 3) + j;
  float v = (k < NIN) ? src[(size_t)o * NIN + k] : 0.f;
  short h = f2bf(v);
  hi[idx] = h;
  lo[idx] = f2bf(v - bf2f(h));
}

#define PK_G  (45 * 4 * 512)
#define PK_B1 (8 * 8 * 512)
#define PK_B2 (4 * 8 * 512)
#define PK_B3 (4 * 90 * 512)
#define PK_TOTAL (PK_G + PK_B1 + PK_B2 + PK_B3)

__global__ void pack_all(const float* __restrict__ gcnW, const float* __restrict__ W1,
                         const float* __restrict__ W2, const float* __restrict__ W3,
                         short* Gh, short* Gl, short* B1h, short* B1l,
                         short* B2h, short* B2l, short* B3h, short* B3l) {
  int idx = blockIdx.x * 256 + threadIdx.x;
  if (idx < PK_G) { pack32_impl(gcnW, Gh, Gl, idx); return; }
  idx -= PK_G;
  if (idx < PK_B1) { pack16_impl(W1, B1h, B1l, 128, 8, 256, idx); return; }
  idx -= PK_B1;
  if (idx < PK_B2) { pack16_impl(W2, B2h, B2l, 128, 8, 128, idx); return; }
  idx -= PK_B2;
  if (idx < PK_B3) { pack16_impl(W3, B3h, B3l, 1433, 90, 128, idx); }
}

// ---------------- Kernel 1: GCN matmul (best measured: R7 structure) ----------------
// 384 threads (6 waves), wave: 32 rows x 64 cols -> block 192 rows. grid 512.
// B: LDS ring-4 x 8KB via global_load_lds; A: asm dwordx4 x4, depth-2; counted vmcnt(6).
__global__ __launch_bounds__(384, 3) void gcn_mfma(
    const float* __restrict__ seq1, const float* __restrict__ seq2,
    const short* __restrict__ Gh, const short* __restrict__ Gl,
    float* __restrict__ fts1, float* __restrict__ fts2)
{
  __shared__ short sB[4][4096];
  const int tid = threadIdx.x;
  const int sid = blockIdx.x >> 8;
  const int bb  = blockIdx.x & 255;
  const float* __restrict__ seq = sid ? seq2 : seq1;
  float* __restrict__ fout = sid ? fts2 : fts1;
  const int w = tid >> 6, lane = tid & 63;
  const int l31 = lane & 31, lg2 = lane >> 5;
  const int row0 = bb * 192 + w * 32;

  f32x16 acc[2];
#pragma unroll
  for (int i = 0; i < 16; ++i) { acc[0][i] = 0.f; acc[1][i] = 0.f; }

  const float* aptr = seq + (size_t)(row0 + l31) * NIN + lg2 * 8;

  auto STAGE = [&](int c, int slot) {
    short* sb = &sB[slot][0];
    const size_t cb = (size_t)c * 256;
#pragma unroll
    for (int i = 0; i < 2; ++i) {
      const int pb = (w * 128 + i * 64) & 511;
      const short* src = (pb < 256) ? (Gh + (cb + pb) * 8 + (size_t)lane * 8)
                                    : (Gl + (cb + (pb - 256)) * 8 + (size_t)lane * 8);
      gload_lds16(src, sb + (pb + lane) * 8);
    }
  };

#define ALOAD(c_, R_)                                                        \
  {                                                                          \
    const float* ad_ = aptr + (c_) * 32;                                     \
    asm volatile(                                                            \
        "global_load_dwordx4 %0, %4, off\n\t"                                \
        "global_load_dwordx4 %1, %4, off offset:16\n\t"                      \
        "global_load_dwordx4 %2, %4, off offset:64\n\t"                      \
        "global_load_dwordx4 %3, %4, off offset:80"                          \
        : "=&v"(R_[0]), "=&v"(R_[1]), "=&v"(R_[2]), "=&v"(R_[3])             \
        : "v"(ad_));                                                         \
  }

  auto SPLIT8 = [&](const f32x4& p, const f32x4& q, bf16x8& H, bf16x8& L) {
    float av[8] = {p[0], p[1], p[2], p[3], q[0], q[1], q[2], q[3]};
#pragma unroll
    for (int j = 0; j < 8; ++j) {
      unsigned u = __float_as_uint(av[j]);
      H[j] = (short)(u >> 16);
      L[j] = f2bf(av[j] - __uint_as_float(u & 0xffff0000u));
    }
  };

  auto COMPUTE = [&](int c, const f32x4* R) {
    bf16x8 Ah0, Al0, Ah1, Al1;
    SPLIT8(R[0], R[1], Ah0, Al0);
    SPLIT8(R[2], R[3], Ah1, Al1);
    const short* bs = &sB[c & 3][0];
    __builtin_amdgcn_s_setprio(1);
#pragma unroll
    for (int ct = 0; ct < 2; ++ct) {
      bf16x8 Bh0 = *(const bf16x8*)(bs + ((0 + ct) * 64 + lane) * 8);
      bf16x8 Bl0 = *(const bf16x8*)(bs + 2048 + ((0 + ct) * 64 + lane) * 8);
      bf16x8 Bh1 = *(const bf16x8*)(bs + ((2 + ct) * 64 + lane) * 8);
      bf16x8 Bl1 = *(const bf16x8*)(bs + 2048 + ((2 + ct) * 64 + lane) * 8);
      acc[ct] = __builtin_amdgcn_mfma_f32_32x32x16_bf16(Ah0, Bh0, acc[ct], 0, 0, 0);
      acc[ct] = __builtin_amdgcn_mfma_f32_32x32x16_bf16(Al0, Bh0, acc[ct], 0, 0, 0);
      acc[ct] = __builtin_amdgcn_mfma_f32_32x32x16_bf16(Ah0, Bl0, acc[ct], 0, 0, 0);
      acc[ct] = __builtin_amdgcn_mfma_f32_32x32x16_bf16(Ah1, Bh1, acc[ct], 0, 0, 0);
      acc[ct] = __builtin_amdgcn_mfma_f32_32x32x16_bf16(Al1, Bh1, acc[ct], 0, 0, 0);
      acc[ct] = __builtin_amdgcn_mfma_f32_32x32x16_bf16(Ah1, Bl1, acc[ct], 0, 0, 0);
    }
    __builtin_amdgcn_s_setprio(0);
  };

  f32x4 A0[4], A1[4];
  STAGE(0, 0); ALOAD(0, A0);
  STAGE(1, 1); ALOAD(1, A1);

#pragma unroll 1
  for (int cc = 0; cc < 42; cc += 2) {
    WAITV(6); BARRIER();
    COMPUTE(cc, A0);
    STAGE(cc + 2, (cc + 2) & 3); ALOAD(cc + 2, A0);
    WAITV(6); BARRIER();
    COMPUTE(cc + 1, A1);
    STAGE(cc + 3, (cc + 3) & 3); ALOAD(cc + 3, A1);
  }
  WAITV(6); BARRIER();
  COMPUTE(42, A0);
  WAITV(0); BARRIER();
  COMPUTE(43, A1);

  // epilogue chunk 44
  {
    const int k0 = 44 * 32 + lg2 * 8;
    float av[16];
#pragma unroll
    for (int j = 0; j < 8; ++j) {
      int ka = k0 + j, kb = k0 + 16 + j;
      av[j]     = (ka < NIN) ? aptr[44 * 32 + j] : 0.f;
      av[8 + j] = (kb < NIN) ? aptr[44 * 32 + 16 + j] : 0.f;
    }
    bf16x8 Ah0, Al0, Ah1, Al1;
#pragma unroll
    for (int j = 0; j < 8; ++j) {
      unsigned u = __float_as_uint(av[j]);
      Ah0[j] = (short)(u >> 16);
      Al0[j] = f2bf(av[j] - __uint_as_float(u & 0xffff0000u));
      u = __float_as_uint(av[8 + j]);
      Ah1[j] = (short)(u >> 16);
      Al1[j] = f2bf(av[8 + j] - __uint_as_float(u & 0xffff0000u));
    }
#pragma unroll
    for (int ct = 0; ct < 2; ++ct) {
      const size_t o0 = ((size_t)(44 * 4 + ct) * 64 + lane) * 8;
      const size_t o1 = ((size_t)(44 * 4 + 2 + ct) * 64 + lane) * 8;
      bf16x8 Bh0 = *(const bf16x8*)(Gh + o0);
      bf16x8 Bl0 = *(const bf16x8*)(Gl + o0);
      bf16x8 Bh1 = *(const bf16x8*)(Gh + o1);
      bf16x8 Bl1 = *(const bf16x8*)(Gl + o1);
      acc[ct] = __builtin_amdgcn_mfma_f32_32x32x16_bf16(Ah0, Bh0, acc[ct], 0, 0, 0);
      acc[ct] = __builtin_amdgcn_mfma_f32_32x32x16_bf16(Al0, Bh0, acc[ct], 0, 0, 0);
      acc[ct] = __builtin_amdgcn_mfma_f32_32x32x16_bf16(Ah0, Bl0, acc[ct], 0, 0, 0);
      acc[ct] = __builtin_amdgcn_mfma_f32_32x32x16_bf16(Ah1, Bh1, acc[ct], 0, 0, 0);
      acc[ct] = __builtin_amdgcn_mfma_f32_32x32x16_bf16(Al1, Bh1, acc[ct], 0, 0, 0);
      acc[ct] = __builtin_amdgcn_mfma_f32_32x32x16_bf16(Ah1, Bl1, acc[ct], 0, 0, 0);
    }
  }

#pragma unroll
  for (int ct = 0; ct < 2; ++ct)
#pragma unroll
    for (int reg = 0; reg < 16; ++reg) {
      int crow = (reg & 3) + 8 * (reg >> 2) + 4 * lg2;
      fout[(size_t)(row0 + crow) * 64 + ct * 32 + l31] = acc[ct][reg];
    }
#undef ALOAD
}

// ---------------- Kernel 2: adj-combine + sinkhorn + t = discW @ c + h1 write ----------------
__global__ __launch_bounds__(256) void sink_kernel(
    const float* __restrict__ fts1, const float* __restrict__ fts2,
    const float* __restrict__ adj1, const float* __restrict__ adj2,
    const float* __restrict__ resc, const float* __restrict__ discW,
    const float* __restrict__ bias, const float* __restrict__ aP,
    float* __restrict__ out, float* __restrict__ tws, float* __restrict__ h1w)
{
  const int b = (blockIdx.x << 2) + (threadIdx.x >> 6);
  const int lane = threadIdx.x & 63;
  const float* F1 = fts1 + (size_t)b * 384;
  const float* F2 = fts2 + (size_t)b * 384;
  float f1[6], f2[6];
#pragma unroll
  for (int m = 0; m < 6; ++m) { f1[m] = F1[m * 64 + lane]; f2[m] = F2[m * 64 + lane]; }
  const float bv = bias[lane];
  const float a = aP[0];
  const float* A1 = adj1 + (size_t)b * 36;
  const float* A2 = adj2 + (size_t)b * 36;
  float h1v[6], h2v[6];
#pragma unroll
  for (int n = 0; n < 6; ++n) {
    float o1 = bv, o2 = bv;
#pragma unroll
    for (int m = 0; m < 6; ++m) {
      o1 = fmaf(A1[n * 6 + m], f1[m], o1);
      o2 = fmaf(A2[n * 6 + m], f2[m], o2);
    }
    h1v[n] = (o1 >= 0.f) ? o1 : a * o1;
    h2v[n] = (o2 >= 0.f) ? o2 : a * o2;
  }
#pragma unroll
  for (int n = 0; n < 6; ++n) h1w[(size_t)b * 384 + n * 64 + lane] = h1v[n];

  float g1[5], g2[5];
#pragma unroll
  for (int i = 0; i < 4; ++i) { g1[i] = h1v[i]; g2[i] = h2v[i]; }
  g1[4] = h1v[5]; g2[4] = h2v[5];
  const float n1 = h1v[4], n2 = h2v[4];

  {
    float cm = (g1[0] + g1[1] + g1[2] + g1[3] + n1) * 0.2f;
    float t = 0.f;
    const float4* W4 = (const float4*)discW;
#pragma unroll 4
    for (int jq = 0; jq < 16; ++jq) {
      float4 wv = W4[lane * 16 + jq];
      t = fmaf(wv.x, __shfl(cm, 4 * jq, 64), t);
      t = fmaf(wv.y, __shfl(cm, 4 * jq + 1, 64), t);
      t = fmaf(wv.z, __shfl(cm, 4 * jq + 2, 64), t);
      t = fmaf(wv.w, __shfl(cm, 4 * jq + 3, 64), t);
    }
    tws[(size_t)b * 64 + lane] = t;
  }

  float in1[5], in2[5];
#pragma unroll
  for (int i = 0; i < 5; ++i) {
    float s = allred64(g1[i] * g1[i]);
    in1[i] = 1.f / fmaxf(sqrtf(s), 1e-12f);
    s = allred64(g2[i] * g2[i]);
    in2[i] = 1.f / fmaxf(sqrtf(s), 1e-12f);
  }
  float cost[25], P[25];
#pragma unroll
  for (int i = 0; i < 5; ++i)
#pragma unroll
    for (int j = 0; j < 5; ++j) {
      float d = allred64(g1[i] * g2[j]);
      float cv = (1.f - d * in1[i] * in2[j]) * resc[(size_t)b * 25 + i * 5 + j];
      cost[i * 5 + j] = cv;
      P[i * 5 + j] = expf(-20.f * cv);
    }
  float r[5], c[5];
  float rs = 0.f, cs = 0.f;
#pragma unroll
  for (int i = 0; i < 5; ++i) {
    float d = allred64(g1[i] * n2); d = (d <= 0.f) ? 1e-8f : d; r[i] = d; rs += d;
    d = allred64(g2[i] * n1);       d = (d <= 0.f) ? 1e-8f : d; c[i] = d; cs += d;
  }
#pragma unroll
  for (int i = 0; i < 5; ++i) { r[i] = r[i] / rs; c[i] = c[i] / cs; }

  float u[5], v[5];
#pragma unroll
  for (int i = 0; i < 5; ++i) u[i] = 0.2f;
#pragma unroll
  for (int it = 0; it < 5; ++it) {
#pragma unroll
    for (int i = 0; i < 5; ++i) {
      float pv = 0.f;
#pragma unroll
      for (int j = 0; j < 5; ++j) pv = fmaf(P[i * 5 + j], u[j], pv);
      v[i] = r[i] / pv;
    }
#pragma unroll
    for (int i = 0; i < 5; ++i) {
      float pu = 0.f;
#pragma unroll
      for (int j = 0; j < 5; ++j) pu = fmaf(P[j * 5 + i], v[j], pu);
      u[i] = c[i] / pu;
    }
  }
  float S = 0.f;
#pragma unroll
  for (int i = 0; i < 5; ++i)
#pragma unroll
    for (int j = 0; j < 5; ++j)
      S += v[i] * P[i * 5 + j] * u[j] * (1.f - cost[i * 5 + j]);
  if (lane == 0) out[(size_t)b * 1436] = expf(S * 2.5f) * 2.f;
}

// ---------------- Kernel 3: fused decoder + discriminator, 8 waves ----------------
// 512 blocks x 512 thr. Block = 16 batches. L3 uses B-hi only (A still split).
__global__ __launch_bounds__(512) void dec_fused(
    const float* __restrict__ h1,
    const short* __restrict__ B1h, const short* __restrict__ B1l,
    const float* __restrict__ b1, const float* __restrict__ a1P,
    const short* __restrict__ B2h, const short* __restrict__ B2l,
    const float* __restrict__ b2, const float* __restrict__ a2P,
    const short* __restrict__ B3h,
    const float* __restrict__ b3, const float* __restrict__ a3P,
    const float* __restrict__ tws, const float* __restrict__ dbP,
    float* __restrict__ out)
{
  __shared__ float xT[16][132];
  __shared__ float x2T[16][132];
  const int tid = threadIdx.x;
  const int w = tid >> 6, lane = tid & 63;
  const int l15 = lane & 15, lg = lane >> 4;
  const int r0 = blockIdx.x * 16;

  // ---- layer 1: K=256, O=128; wave w -> nf = w ----
  f32x4 acc1 = (f32x4){0.f, 0.f, 0.f, 0.f};
#pragma unroll
  for (int c = 0; c < 8; ++c) {
    const float* ap = h1 + (size_t)(r0 + l15) * 384 + c * 32 + lg * 8;
    float4 p = *(const float4*)ap;
    float4 q = *(const float4*)(ap + 4);
    float av[8] = {p.x, p.y, p.z, p.w, q.x, q.y, q.z, q.w};
    bf16x8 Ah, Al;
#pragma unroll
    for (int j = 0; j < 8; ++j) { short h = f2bf(av[j]); Ah[j] = h; Al[j] = f2bf(av[j] - bf2f(h)); }
    size_t off = (((size_t)(c * 8 + w)) << 9) + (size_t)lane * 8;
    bf16x8 Bh = *(const bf16x8*)(B1h + off);
    bf16x8 Bl = *(const bf16x8*)(B1l + off);
    acc1 = __builtin_amdgcn_mfma_f32_16x16x32_bf16(Ah, Bh, acc1, 0, 0, 0);
    acc1 = __builtin_amdgcn_mfma_f32_16x16x32_bf16(Al, Bh, acc1, 0, 0, 0);
    acc1 = __builtin_amdgcn_mfma_f32_16x16x32_bf16(Ah, Bl, acc1, 0, 0, 0);
  }
  {
    const float a1 = a1P[0];
    int o = w * 16 + l15;
    float bvv = b1[o];
#pragma unroll
    for (int j = 0; j < 4; ++j) {
      float v = acc1[j] + bvv;
      xT[lg * 4 + j][o] = (v >= 0.f) ? v : a1 * v;
    }
  }
  __syncthreads();

  // ---- layer 2: K=128, O=128; wave w -> nf = w ----
  acc1 = (f32x4){0.f, 0.f, 0.f, 0.f};
#pragma unroll
  for (int c = 0; c < 4; ++c) {
    const float* ap = &xT[l15][c * 32 + lg * 8];
    float4 p = *(const float4*)ap;
    float4 q = *(const float4*)(ap + 4);
    float av[8] = {p.x, p.y, p.z, p.w, q.x, q.y, q.z, q.w};
    bf16x8 Ah, Al;
#pragma unroll
    for (int j = 0; j < 8; ++j) { short h = f2bf(av[j]); Ah[j] = h; Al[j] = f2bf(av[j] - bf2f(h)); }
    size_t off = (((size_t)(c * 8 + w)) << 9) + (size_t)lane * 8;
    bf16x8 Bh = *(const bf16x8*)(B2h + off);
    bf16x8 Bl = *(const bf16x8*)(B2l + off);
    acc1 = __builtin_amdgcn_mfma_f32_16x16x32_bf16(Ah, Bh, acc1, 0, 0, 0);
    acc1 = __builtin_amdgcn_mfma_f32_16x16x32_bf16(Al, Bh, acc1, 0, 0, 0);
    acc1 = __builtin_amdgcn_mfma_f32_16x16x32_bf16(Ah, Bl, acc1, 0, 0, 0);
  }
  {
    const float a2 = a2P[0];
    int o = w * 16 + l15;
    float bvv = b2[o];
#pragma unroll
    for (int j = 0; j < 4; ++j) {
      float v = acc1[j] + bvv;
      x2T[lg * 4 + j][o] = (v >= 0.f) ? v : a2 * v;
    }
  }
  __syncthreads();

  // ---- layer 3: K=128, O=1433; wave w -> nf = w + 8t; B hi-only ----
  bf16x8 A3h[4], A3l[4];
#pragma unroll
  for (int c = 0; c < 4; ++c) {
    const float* ap = &x2T[l15][c * 32 + lg * 8];
    float4 p = *(const float4*)ap;
    float4 q = *(const float4*)(ap + 4);
    float av[8] = {p.x, p.y, p.z, p.w, q.x, q.y, q.z, q.w};
#pragma unroll
    for (int j = 0; j < 8; ++j) {
      short h = f2bf(av[j]); A3h[c][j] = h; A3l[c][j] = f2bf(av[j] - bf2f(h));
    }
  }
  const float a3 = a3P[0];
#pragma unroll 1
  for (int t = 0; t < 12; ++t) {
    const int nf = w + 8 * t;
    if (nf >= 90) break;
    f32x4 acc = (f32x4){0.f, 0.f, 0.f, 0.f};
#pragma unroll
    for (int c = 0; c < 4; ++c) {
      size_t off = (((size_t)(c * 90 + nf)) << 9) + (size_t)lane * 8;
      bf16x8 Bh = *(const bf16x8*)(B3h + off);
      acc = __builtin_amdgcn_mfma_f32_16x16x32_bf16(A3h[c], Bh, acc, 0, 0, 0);
      acc = __builtin_amdgcn_mfma_f32_16x16x32_bf16(A3l[c], Bh, acc, 0, 0, 0);
    }
    const int o = nf * 16 + l15;
    if (o < NIN) {
      float bvv = b3[o];
#pragma unroll
      for (int j = 0; j < 4; ++j) {
        float v = acc[j] + bvv;
        v = (v >= 0.f) ? v : a3 * v;
        out[(size_t)(r0 + lg * 4 + j) * 1436 + 1 + o] = v;
      }
    }
  }

  // ---- discriminator logits (2 batches per wave) ----
  {
    const float db = dbP[0];
#pragma unroll
    for (int i = 0; i < 2; ++i) {
      const int bb = r0 + 2 * w + i;
      float hp = h1[(size_t)bb * 384 + 5 * 64 + lane];
      float t0 = tws[(size_t)bb * 64 + lane];
      const int bp = (bb == 0) ? (BB - 2) : (bb - 1);
      float tp = tws[(size_t)bp * 64 + lane];
      float s1 = allred64(hp * t0);
      float s2 = allred64(hp * tp);
      if (lane == 0) {
        out[(size_t)bb * 1436 + 1434] = s1 + db;
        out[(size_t)bb * 1436 + 1435] = s2 + db;
      }
    }
  }
}

extern "C" void kernel_launch(void* const* d_in, const int* in_sizes, int n_in,
                              void* d_out, int out_size, void* d_ws, size_t ws_size,
                              hipStream_t stream) {
  (void)in_sizes; (void)n_in; (void)out_size; (void)ws_size;
  const float* seq1  = (const float*)d_in[0];
  const float* seq2  = (const float*)d_in[1];
  const float* adj1  = (const float*)d_in[2];
  const float* adj2  = (const float*)d_in[3];
  const float* resc  = (const float*)d_in[4];
  const float* gcnW  = (const float*)d_in[5];
  const float* gcnB  = (const float*)d_in[6];
  const float* gcnA  = (const float*)d_in[7];
  const float* W1    = (const float*)d_in[8];
  const float* b1    = (const float*)d_in[9];
  const float* a1    = (const float*)d_in[10];
  const float* W2    = (const float*)d_in[11];
  const float* b2    = (const float*)d_in[12];
  const float* a2    = (const float*)d_in[13];
  const float* W3    = (const float*)d_in[14];
  const float* b3    = (const float*)d_in[15];
  const float* a3    = (const float*)d_in[16];
  const float* discW = (const float*)d_in[17];
  const float* discB = (const float*)d_in[18];

  float* fts1 = (float*)d_ws;
  float* fts2 = fts1 + (size_t)BB * SUBG * NH;
  float* h1   = fts2 + (size_t)BB * SUBG * NH;
  float* tws  = h1  + (size_t)BB * SUBG * NH;
  short* Gh   = (short*)(tws + (size_t)BB * 64);
  short* Gl   = Gh  + PK_G;
  short* B1h  = Gl  + PK_G;
  short* B1l  = B1h + PK_B1;
  short* B2h  = B1l + PK_B1;
  short* B2l  = B2h + PK_B2;
  short* B3h  = B2l + PK_B2;
  short* B3l  = B3h + PK_B3;
  float* out  = (float*)d_out;

  pack_all<<<(PK_TOTAL + 255) / 256, 256, 0, stream>>>(
      gcnW, W1, W2, W3, Gh, Gl, B1h, B1l, B2h, B2l, B3h, B3l);

  gcn_mfma<<<512, 384, 0, stream>>>(seq1, seq2, Gh, Gl, fts1, fts2);
  sink_kernel<<<2048, 256, 0, stream>>>(fts1, fts2, adj1, adj2, resc, discW, gcnB, gcnA,
                                        out, tws, h1);
  dec_fused<<<512, 512, 0, stream>>>(h1, B1h, B1l, b1, a1, B2h, B2l, b2, a2,
                                     B3h, b3, a3, tws, discB, out);
}